// Round 10
// baseline (1314.056 us; speedup 1.0000x reference)
//
#include <hip/hip_runtime.h>
#include <math.h>

// MPNN on MI355X. R29 = R28 + gru stall-merge + coalesced p write.
// R28 counters: gru 148us, Mfma 18.7/VALU 21.8/HBM 25.5/Occ 29 -> latency
// bound between barriers; WRITE 208MB vs 131 logical (64B partial lines).
// Changes (gru only; everything else = R28 validated):
//  (1) Phase A stages Smean (16KB, region R0) AND h k-half-0 into the
//      FREE 16KB (region R1) -> all 8 global loads pipeline in one
//      latency window; Phase B computes gate-x + gate-h kt{0,1} (288
//      MFMAs) before the next stall; Phase C stages only h-half-1 into
//      R0. Epilogue hv region selected by jg (wave-uniform): jg=0 -> R1,
//      jg=1 -> R0. Zero extra VGPR (R26 lesson: acc lives in AGPR,
//      combined budget ~212 of 512/3-wave; no headroom for reg prefetch).
//  (2) p written via f32 overlay on sm (stride 130, bank-safe), barrier,
//      256 threads store row-major 128B-contiguous float4 -> full lines.
//      sm grows to 33536B (3 x 33.5 = 100.6KB <= 160KB: still 3 blk/CU).
// Barriers 7 (was 5+0, now 5+2 for p path but A/C merged saves latency).
// MFMA/wave unchanged 528. Arithmetic bit-identical (absmax 1.22e-4).

#define DDIM 128
#define NTOT 128000
#define HBYTES 65536000ULL   // 128000*128*4
#define EBLK 128

typedef unsigned short u16;
using f32x4 = __attribute__((ext_vector_type(4))) float;
using s16x8 = __attribute__((ext_vector_type(8))) short;

__device__ __forceinline__ float fast_rcp(float x) {
    return __builtin_amdgcn_rcpf(x);
}
// A&S 7.1.26 erf, |abs err| <= 1.5e-7; raw v_rcp (1 ulp) for the divide.
__device__ __forceinline__ float gelu_fast(float x) {
    const float ax = fabsf(x) * 0.70710678118654752440f;
    const float t  = fast_rcp(1.0f + 0.3275911f * ax);
    const float poly = t * (0.254829592f + t * (-0.284496736f +
                       t * (1.421413741f + t * (-1.453152027f +
                       t * 1.061405429f))));
    const float e = __expf(-ax * ax);
    const float erfax = 1.0f - poly * e;
    const float erfv = copysignf(erfax, x);
    return 0.5f * x * (1.0f + erfv);
}
__device__ __forceinline__ float sigmoid_fast(float x) {
    return fast_rcp(1.0f + __expf(-x));
}
__device__ __forceinline__ float tanh_fast(float x) {
    const float e = __expf(2.0f * x);     // tanh = 1 - 2/(e^{2x}+1)
    return 1.0f - 2.0f * fast_rcp(e + 1.0f);
}
__device__ __forceinline__ u16 f2bf(float x) {            // RNE f32->bf16
    unsigned u = __float_as_uint(x);
    u += 0x7fffu + ((u >> 16) & 1u);
    return (u16)(u >> 16);
}
__device__ __forceinline__ float bf2f(u16 h) {
    return __uint_as_float(((unsigned)h) << 16);
}

__global__ __launch_bounds__(256) void embed_kernel(
    const int* __restrict__ inp, const float* __restrict__ table,
    float* __restrict__ h)
{
    int gid = blockIdx.x * 256 + threadIdx.x;
    if (gid >= NTOT * 32) return;
    int row = gid >> 5;
    int q   = gid & 31;
    int b   = row / 4000;
    int n   = (row % 4000) % 1000;
    int e   = inp[b * 1000 + n];
    ((float4*)h)[gid] = ((const float4*)table)[e * 32 + q];
}

__global__ __launch_bounds__(256) void hist_kernel(
    const int* __restrict__ ni, const int* __restrict__ bi, int E,
    int* __restrict__ deg)
{
    int g = blockIdx.x * 256 + threadIdx.x;
    if (g < E)          atomicAdd(&deg[bi[g]], 1);
    else if (g < 2 * E) atomicAdd(&deg[ni[g - E]], 1);
}

__global__ __launch_bounds__(256) void blockscan_kernel(
    const int* __restrict__ deg, int* __restrict__ offp, int* __restrict__ bsum)
{
    __shared__ int s[256];
    int tid = threadIdx.x;
    int i = blockIdx.x * 256 + tid;
    int v = deg[i];
    s[tid] = v;
    __syncthreads();
    for (int off = 1; off < 256; off <<= 1) {
        int t = (tid >= off) ? s[tid - off] : 0;
        __syncthreads();
        s[tid] += t;
        __syncthreads();
    }
    offp[i] = s[tid] - v;
    if (tid == 255) bsum[blockIdx.x] = s[255];
}

__global__ __launch_bounds__(512) void bscan_kernel(
    const int* __restrict__ bsum, int* __restrict__ bexc, int nb)
{
    __shared__ int s[512];
    int t = threadIdx.x;
    int v = (t < nb) ? bsum[t] : 0;
    s[t] = v;
    __syncthreads();
    for (int off = 1; off < 512; off <<= 1) {
        int u = (t >= off) ? s[t - off] : 0;
        __syncthreads();
        s[t] += u;
        __syncthreads();
    }
    if (t < nb) bexc[t] = s[t] - v;
}

__global__ __launch_bounds__(256) void fill_kernel(
    const int* __restrict__ ni, const int* __restrict__ bi, int E,
    const int* __restrict__ offp, const int* __restrict__ bexc,
    int* __restrict__ cursor, int* __restrict__ elist, int* __restrict__ slotseg)
{
    int g = blockIdx.x * 256 + threadIdx.x;
    if (g >= 2 * E) return;
    int seg = (g < E) ? bi[g] : ni[g - E];
    int pos = atomicAdd(&cursor[seg], 1);
    int slot = offp[seg] + bexc[seg >> 8] + pos;
    elist[slot] = g;
    slotseg[slot] = seg;
}

// Segments straddling a 32-slot boundary — the only atomicAdd targets.
__global__ __launch_bounds__(256) void straddle_kernel(
    const int* __restrict__ slotseg, int nblocks32,
    int* __restrict__ list, int* __restrict__ count)
{
    int b = blockIdx.x * 256 + threadIdx.x + 1;
    if (b >= nblocks32) return;
    int s = slotseg[b * 32];
    if (s >= 0 && slotseg[b * 32 - 1] == s) {
        int pos = atomicAdd(count, 1);
        list[pos] = s;
    }
}

__global__ __launch_bounds__(64) void zero_rows_kernel(
    const int* __restrict__ list, const int* __restrict__ count,
    float* __restrict__ sbuf)   // 64-wide rows
{
    int i = blockIdx.x;
    if (i >= *count) return;
    int seg = list[i];
    float4* row = (float4*)(sbuf + (size_t)seg * 64);
    if (threadIdx.x < 16) row[threadIdx.x] = make_float4(0.f, 0.f, 0.f, 0.f);
}

// ---------------------------------------------------------------------------
// B-fragment packers (run once per launch). Shared frag map:
// lane l, elem j -> k = kt*32+(l>>4)*8+j, n = nt*16+(l&15).
// ---------------------------------------------------------------------------

// Composite gate-x B: C = Wout[64x128] @ Wx[128x384], slots z|r|xh.
// idx = (kt*24 + g*8 + nt)*512 + lane*8 + j; kt in {0,1}, g in {0,1,2}.
__global__ __launch_bounds__(256) void pack_gateBx_kernel(
    const float* __restrict__ Wout, const float* __restrict__ Wx,
    u16* __restrict__ BH, u16* __restrict__ BL)
{
    int idx = blockIdx.x * 256 + threadIdx.x;   // 24576 total
    if (idx >= 24576) return;
    int j    = idx & 7;
    int lane = (idx >> 3) & 63;
    int tile = idx >> 9;
    int nt   = tile & 7;
    int g    = (tile >> 3) % 3;
    int kt   = tile / 24;                        // 0..1
    int k   = kt * 32 + (lane >> 4) * 8 + j;     // 0..63
    int col = g * 128 + nt * 16 + (lane & 15);   // 0..383
    float acc = 0.0f;
    for (int t = 0; t < 128; ++t)
        acc = fmaf(Wout[k * 128 + t], Wx[t * 384 + col], acc);
    u16 hb = f2bf(acc);
    BH[idx] = hb;
    BL[idx] = f2bf(acc - bf2f(hb));
}

// Gate-h B: Wh[128x384], slots z|r|hh (cols 0|128|256).
// idx = (kt*24 + s*8 + nt)*512 + lane*8 + j; kt in {0..3}, s in {0,1,2}.
__global__ __launch_bounds__(256) void pack_gateBh_kernel(
    const float* __restrict__ Wh, u16* __restrict__ BH, u16* __restrict__ BL)
{
    int idx = blockIdx.x * 256 + threadIdx.x;   // 49152 total
    if (idx >= 49152) return;
    int j    = idx & 7;
    int lane = (idx >> 3) & 63;
    int tile = idx >> 9;
    int nt   = tile & 7;
    int s    = (tile >> 3) % 3;
    int kt   = tile / 24;                        // 0..3
    int k    = kt * 32 + (lane >> 4) * 8 + j;    // 0..127
    int col  = ((s == 2) ? 256 : s * 128) + nt * 16 + (lane & 15);
    float v = Wh[k * 384 + col];
    u16 hb = f2bf(v);
    BH[idx] = hb;
    BL[idx] = f2bf(v - bf2f(hb));
}

// Composite gate bias: bc[n] = sum_t bout[t] * Wx[t*384+n], n in [0,384).
__global__ __launch_bounds__(256) void pack_gbias_kernel(
    const float* __restrict__ bout, const float* __restrict__ Wx,
    float* __restrict__ bc)
{
    int n = blockIdx.x * 256 + threadIdx.x;
    if (n >= 384) return;
    float acc = 0.0f;
    for (int t = 0; t < 128; ++t)
        acc = fmaf(bout[t], Wx[t * 384 + n], acc);
    bc[n] = acc;
}

// node_pre B: [K=128][N=128], n<64 -> Win rows 0..127, n>=64 -> rows 128..255.
__global__ __launch_bounds__(256) void pack_preB_kernel(
    const float* __restrict__ Win, u16* __restrict__ BH, u16* __restrict__ BL)
{
    int idx = blockIdx.x * 256 + threadIdx.x;   // 16384 total
    if (idx >= 16384) return;
    int j    = idx & 7;
    int lane = (idx >> 3) & 63;
    int nt2  = (idx >> 9) & 7;
    int kt2  = idx >> 12;                        // 0..3
    int k = kt2 * 32 + (lane >> 4) * 8 + j;      // 0..127
    int n = nt2 * 16 + (lane & 15);              // 0..127
    float v = (n < 64) ? Win[k * 64 + n] : Win[(128 + k) * 64 + (n - 64)];
    u16 hb = f2bf(v);
    BH[idx] = hb;
    BL[idx] = f2bf(v - bf2f(hb));
}

// Edge-MLP hidden B: 3 layers x [K=64][N=64]. idx=(L*8+kt*4+nt)*512+lane*8+j.
__global__ __launch_bounds__(256) void pack_hidB_kernel(
    const float* __restrict__ Whid, u16* __restrict__ BH, u16* __restrict__ BL)
{
    int idx = blockIdx.x * 256 + threadIdx.x;   // 12288 total
    if (idx >= 12288) return;
    int j    = idx & 7;
    int lane = (idx >> 3) & 63;
    int nt   = (idx >> 9) & 3;
    int kt   = (idx >> 11) & 1;
    int L    = idx >> 12;
    int k = kt * 32 + (lane >> 4) * 8 + j;       // 0..63
    int n = nt * 16 + (lane & 15);               // 0..63
    float v = Whid[L * 4096 + k * 64 + n];
    u16 hb = f2bf(v);
    BH[idx] = hb;
    BL[idx] = f2bf(v - bf2f(hb));
}

// ---------------------------------------------------------------------------
// Initial p via MFMA (validated R25-R28). 128 nodes / 512 thr / 8 waves.
// ---------------------------------------------------------------------------
__global__ __launch_bounds__(512, 2) void node_pre_mfma(
    const float* __restrict__ h,
    const u16* __restrict__ BpH, const u16* __restrict__ BpL,
    const float* __restrict__ binp, float* __restrict__ pout)
{
    __shared__ short sm[32768];   // hi [0,16384), lo [16384,32768) shorts
    const int tid  = threadIdx.x;
    const int lane = tid & 63;
    const int w    = tid >> 6;    // 0..7
    const int jg   = w & 1;
    const int mh   = w >> 1;      // 0..3
    const int nbase = blockIdx.x * 128;

    const int mS = tid >> 2, q = tid & 3;
    const int nodeS = nbase + mS;
    const int laneS = (mS & 15) + 16 * q;
    const int seg_m = mS >> 4;

    #pragma unroll
    for (int c = 0; c < 4; ++c) {
        const int kl = c * 32 + q * 8;
        const float* src = h + (size_t)nodeS * DDIM + kl;
        const float4 v0 = ((const float4*)src)[0];
        const float4 v1 = ((const float4*)src)[1];
        float xv[8] = { v0.x, v0.y, v0.z, v0.w, v1.x, v1.y, v1.z, v1.w };
        s16x8 hi8, lo8;
        #pragma unroll
        for (int i = 0; i < 8; ++i) {
            u16 hb = f2bf(xv[i]);
            hi8[i] = (short)hb;
            lo8[i] = (short)f2bf(xv[i] - bf2f(hb));
        }
        const int off = (c * 8 + seg_m) * 512 + laneS * 8;
        *(s16x8*)(sm + off)         = hi8;
        *(s16x8*)(sm + off + 16384) = lo8;
    }
    __syncthreads();

    f32x4 acc2[2][4];
    #pragma unroll
    for (int mf = 0; mf < 2; ++mf)
        #pragma unroll
        for (int t4 = 0; t4 < 4; ++t4)
            acc2[mf][t4] = (f32x4){0.f, 0.f, 0.f, 0.f};

    const s16x8* Ph8 = (const s16x8*)BpH;
    const s16x8* Pl8 = (const s16x8*)BpL;
    #pragma unroll
    for (int kt2 = 0; kt2 < 4; ++kt2) {
        const int a0off = (kt2 * 8 + 2 * mh) * 512 + lane * 8;
        const s16x8 aH0 = *(const s16x8*)(sm + a0off);
        const s16x8 aL0 = *(const s16x8*)(sm + 16384 + a0off);
        const s16x8 aH1 = *(const s16x8*)(sm + a0off + 512);
        const s16x8 aL1 = *(const s16x8*)(sm + 16384 + a0off + 512);
        #pragma unroll
        for (int t4 = 0; t4 < 4; ++t4) {
            const int idx = (kt2 * 8 + jg * 4 + t4) * 64 + lane;
            const s16x8 bH = Ph8[idx];
            const s16x8 bL = Pl8[idx];
            acc2[0][t4] = __builtin_amdgcn_mfma_f32_16x16x32_bf16(aH0, bH, acc2[0][t4], 0, 0, 0);
            acc2[0][t4] = __builtin_amdgcn_mfma_f32_16x16x32_bf16(aH0, bL, acc2[0][t4], 0, 0, 0);
            acc2[0][t4] = __builtin_amdgcn_mfma_f32_16x16x32_bf16(aL0, bH, acc2[0][t4], 0, 0, 0);
            acc2[1][t4] = __builtin_amdgcn_mfma_f32_16x16x32_bf16(aH1, bH, acc2[1][t4], 0, 0, 0);
            acc2[1][t4] = __builtin_amdgcn_mfma_f32_16x16x32_bf16(aH1, bL, acc2[1][t4], 0, 0, 0);
            acc2[1][t4] = __builtin_amdgcn_mfma_f32_16x16x32_bf16(aL1, bH, acc2[1][t4], 0, 0, 0);
        }
    }
    #pragma unroll
    for (int mf = 0; mf < 2; ++mf) {
        const int mtile = 2 * mh + mf;
        #pragma unroll
        for (int t4 = 0; t4 < 4; ++t4) {
            const int n = jg * 64 + t4 * 16 + (lane & 15);
            const float badd = (n < 64) ? binp[n] : 0.0f;
            #pragma unroll
            for (int r = 0; r < 4; ++r) {
                const int m = mtile * 16 + (lane >> 4) * 4 + r;
                pout[(size_t)(nbase + m) * DDIM + n] = acc2[mf][t4][r] + badd;
            }
        }
    }
}

// ---------------------------------------------------------------------------
// MFMA edge MLP (R24, validated). 512 threads / 128 slots per block.
// ---------------------------------------------------------------------------
__global__ __launch_bounds__(512) void edge_mlp_mfma(
    const int* __restrict__ ni, const int* __restrict__ bi, int E,
    const int* __restrict__ elist, const int* __restrict__ slotseg,
    const float* __restrict__ p,
    const u16* __restrict__ BhH, const u16* __restrict__ BhL,
    const float* __restrict__ bhid,
    float* __restrict__ sbuf)
{
    __shared__ short smA[17408];      // 34816B; frags [0,16384) shorts
    __shared__ int   segLDS[EBLK];
    __shared__ int   segedge[2];
    float* scat = (float*)smA;

    const int tid  = threadIdx.x;
    const int lane = tid & 63;
    const int w    = tid >> 6;        // wave = m-tile
    const int s0   = blockIdx.x * EBLK;

    if (tid < 128) segLDS[tid] = slotseg[s0 + tid];
    if (tid == 0) segedge[0] = slotseg[s0 - 1];
    if (tid == 1) segedge[1] = slotseg[s0 + EBLK];

    {
        const int m  = (tid & 15) | (w << 4);
        const int gg = (tid >> 4) & 3;
        const int slot = s0 + m;
        const int g = elist[slot];
        int first, second;
        if (g < E) { first = ni[g];     second = bi[g];     }
        else       { first = bi[g - E]; second = ni[g - E]; }
        #pragma unroll
        for (int kt = 0; kt < 2; ++kt) {
            const int k0 = kt * 32 + gg * 8;
            const float4* pa = (const float4*)(p + (size_t)first  * DDIM + k0);
            const float4* pb = (const float4*)(p + (size_t)second * DDIM + 64 + k0);
            const float4 a0 = pa[0], a1 = pa[1], b0 = pb[0], b1 = pb[1];
            float x[8] = { a0.x + b0.x, a0.y + b0.y, a0.z + b0.z, a0.w + b0.w,
                           a1.x + b1.x, a1.y + b1.y, a1.z + b1.z, a1.w + b1.w };
            s16x8 hi8, lo8;
            #pragma unroll
            for (int j = 0; j < 8; ++j) {
                const float v = gelu_fast(x[j]);
                u16 hb = f2bf(v);
                hi8[j] = (short)hb;
                lo8[j] = (short)f2bf(v - bf2f(hb));
            }
            const int off = (kt * 8 + w) * 512 + lane * 8;
            *(s16x8*)(smA + off)        = hi8;
            *(s16x8*)(smA + 8192 + off) = lo8;
        }
    }
    // no barrier: wave w staged exactly the segments (kt*8+w) it reads.

    const int mt = w;
    for (int L = 0; L < 2; ++L) {
        f32x4 acc[4];
        #pragma unroll
        for (int nt = 0; nt < 4; ++nt) {
            const float bv = bhid[L * 64 + nt * 16 + (lane & 15)];
            acc[nt] = (f32x4){bv, bv, bv, bv};
        }
        #pragma unroll
        for (int kt = 0; kt < 2; ++kt) {
            const s16x8 aH = *(const s16x8*)(smA + (kt * 8 + mt) * 512 + lane * 8);
            const s16x8 aL = *(const s16x8*)(smA + 8192 + (kt * 8 + mt) * 512 + lane * 8);
            #pragma unroll
            for (int nt = 0; nt < 4; ++nt) {
                const int bidx = (L * 8 + kt * 4 + nt) * 64 + lane;
                const s16x8 bH = ((const s16x8*)BhH)[bidx];
                const s16x8 bL = ((const s16x8*)BhL)[bidx];
                acc[nt] = __builtin_amdgcn_mfma_f32_16x16x32_bf16(aH, bH, acc[nt], 0, 0, 0);
                acc[nt] = __builtin_amdgcn_mfma_f32_16x16x32_bf16(aH, bL, acc[nt], 0, 0, 0);
                acc[nt] = __builtin_amdgcn_mfma_f32_16x16x32_bf16(aL, bH, acc[nt], 0, 0, 0);
            }
        }
        #pragma unroll
        for (int nt = 0; nt < 4; ++nt) {
            #pragma unroll
            for (int r = 0; r < 4; ++r) {
                const float v = gelu_fast(acc[nt][r]);
                const int ml  = (lane >> 4) * 4 + r;
                const int k   = nt * 16 + (lane & 15);
                const int kt2 = k >> 5, gg = (k >> 3) & 3, j = k & 7;
                const int off = (kt2 * 8 + mt) * 512 + (ml + 16 * gg) * 8 + j;
                u16 hb = f2bf(v);
                smA[off]        = (short)hb;
                smA[8192 + off] = (short)f2bf(v - bf2f(hb));
            }
        }
    }

    float gl[4][4];
    {
        f32x4 acc[4];
        #pragma unroll
        for (int nt = 0; nt < 4; ++nt) {
            const float bv = bhid[2 * 64 + nt * 16 + (lane & 15)];
            acc[nt] = (f32x4){bv, bv, bv, bv};
        }
        #pragma unroll
        for (int kt = 0; kt < 2; ++kt) {
            const s16x8 aH = *(const s16x8*)(smA + (kt * 8 + mt) * 512 + lane * 8);
            const s16x8 aL = *(const s16x8*)(smA + 8192 + (kt * 8 + mt) * 512 + lane * 8);
            #pragma unroll
            for (int nt = 0; nt < 4; ++nt) {
                const int bidx = (2 * 8 + kt * 4 + nt) * 64 + lane;
                const s16x8 bH = ((const s16x8*)BhH)[bidx];
                const s16x8 bL = ((const s16x8*)BhL)[bidx];
                acc[nt] = __builtin_amdgcn_mfma_f32_16x16x32_bf16(aH, bH, acc[nt], 0, 0, 0);
                acc[nt] = __builtin_amdgcn_mfma_f32_16x16x32_bf16(aH, bL, acc[nt], 0, 0, 0);
                acc[nt] = __builtin_amdgcn_mfma_f32_16x16x32_bf16(aL, bH, acc[nt], 0, 0, 0);
            }
        }
        #pragma unroll
        for (int nt = 0; nt < 4; ++nt)
            #pragma unroll
            for (int r = 0; r < 4; ++r)
                gl[nt][r] = gelu_fast(acc[nt][r]);
    }

    __syncthreads();   // all frag reads done before scat overlays them
    #pragma unroll
    for (int nt = 0; nt < 4; ++nt)
        #pragma unroll
        for (int r = 0; r < 4; ++r)
            scat[(mt * 16 + (lane >> 4) * 4 + r) * 68 + nt * 16 + (lane & 15)]
                = gl[nt][r];
    __syncthreads();

    if (tid < 256) {
        const int col = tid & 63;
        const int r0  = (tid >> 6) * 32;
        const int r1  = r0 + 32;
        int   runSeg = -2;
        float runacc = 0.0f;
        bool  leftC  = true;
        for (int rowi = r0; rowi < r1; ++rowi) {
            const int sg = segLDS[rowi];
            const float v = scat[rowi * 68 + col];
            if (sg != runSeg) {
                if (runSeg >= 0) {
                    float* pp = sbuf + (size_t)runSeg * 64 + col;
                    if (leftC) *pp = runacc;
                    else       atomicAdd(pp, runacc);
                }
                runSeg = sg;
                runacc = v;
                if (rowi == r0) {
                    const int prev = (rowi == 0) ? segedge[0] : segLDS[rowi - 1];
                    leftC = (prev != sg);
                } else {
                    leftC = true;
                }
            } else {
                runacc += v;
            }
        }
        if (runSeg >= 0) {
            const int nxt = (r1 == 128) ? segedge[1] : segLDS[r1];
            const bool rightC = (nxt != runSeg);
            float* pp = sbuf + (size_t)runSeg * 64 + col;
            if (leftC && rightC) *pp = runacc;
            else                 atomicAdd(pp, runacc);
        }
    }
}

// ---------------------------------------------------------------------------
// MFMA GRU, R29: merged-stall schedule + coalesced p write.
// 64 nodes / 256 thr / 4 waves; wave w: jg=w&1, mh=w>>1.
// LDS regions (shorts): R0 hi [0,4096) lo [8192,12288);
//                       R1 hi [4096,8192) lo [12288,16384).
//  A: stage Smean->R0 AND h k-half0->R1 (8 loads, one latency)  [barrier]
//  B: gate-x GEMM (R0) + gate-h kt{0,1} (R1) = 288 MFMA         [barrier]
//  C: stage h k-half1 -> R0                                      [barrier]
//  D: gate-h kt{2,3} (R0)
//  E: epilogue (hv: jg=0->R1, jg=1->R0), write hio               [barrier]
//  F: scatter h' pre-frags (full 16KB)                           [barrier]
//  G: node_pre GEMM                                              [barrier]
//     p -> f32 overlay (stride 130)                              [barrier]
//     coalesced 128B row-major store.
// ---------------------------------------------------------------------------
__global__ __launch_bounds__(256, 3) void gru_mfma_kernel(
    float* __restrict__ hio, const float* __restrict__ Ssum,
    const int* __restrict__ deg,
    const u16* __restrict__ BxH, const u16* __restrict__ BxL,
    const u16* __restrict__ BhH, const u16* __restrict__ BhL,
    const float* __restrict__ bc,
    const float* __restrict__ bi_, const float* __restrict__ br_,
    const u16* __restrict__ BpH, const u16* __restrict__ BpL,
    const float* __restrict__ binp,
    float* __restrict__ pout)
{
    __shared__ short sm[16768];   // 33536B; frag planes use [0,16384)
    const int tid  = threadIdx.x;
    const int lane = tid & 63;
    const int w    = tid >> 6;    // 0..3
    const int jg   = w & 1;
    const int mh   = w >> 1;      // m-half
    const int nbase = blockIdx.x * 64;

    const int mS = tid >> 2, q = tid & 3;   // staging row / lane-quarter
    const int nodeS = nbase + mS;
    const int laneS = (mS & 15) + 16 * q;
    const int seg_m = mS >> 4;
    const int dg = deg[nodeS];
    const float ci = (dg > 0) ? fast_rcp((float)dg) : 0.0f;

    // ---- Phase A: stage Smean (R0) + h k-half0 (R1); loads pipeline ----
    {
        // issue all 8 loads first (compiler keeps program order of loads)
        float4 sv[4], hv0[4];
        #pragma unroll
        for (int c = 0; c < 2; ++c) {
            const int kl = c * 32 + q * 8;
            sv[c * 2]     = ((const float4*)(Ssum + (size_t)nodeS * 64 + kl))[0];
            sv[c * 2 + 1] = ((const float4*)(Ssum + (size_t)nodeS * 64 + kl))[1];
            hv0[c * 2]     = ((const float4*)(hio + (size_t)nodeS * DDIM + kl))[0];
            hv0[c * 2 + 1] = ((const float4*)(hio + (size_t)nodeS * DDIM + kl))[1];
        }
        #pragma unroll
        for (int c = 0; c < 2; ++c) {
            float xv[8] = { sv[c*2].x * ci, sv[c*2].y * ci, sv[c*2].z * ci, sv[c*2].w * ci,
                            sv[c*2+1].x * ci, sv[c*2+1].y * ci, sv[c*2+1].z * ci, sv[c*2+1].w * ci };
            s16x8 hi8, lo8;
            #pragma unroll
            for (int i = 0; i < 8; ++i) {
                u16 hb = f2bf(xv[i]);
                hi8[i] = (short)hb;
                lo8[i] = (short)f2bf(xv[i] - bf2f(hb));
            }
            const int off = (c * 4 + seg_m) * 512 + laneS * 8;
            *(s16x8*)(sm + off)        = hi8;
            *(s16x8*)(sm + off + 8192) = lo8;
        }
        #pragma unroll
        for (int c = 0; c < 2; ++c) {
            float xv[8] = { hv0[c*2].x, hv0[c*2].y, hv0[c*2].z, hv0[c*2].w,
                            hv0[c*2+1].x, hv0[c*2+1].y, hv0[c*2+1].z, hv0[c*2+1].w };
            s16x8 hi8, lo8;
            #pragma unroll
            for (int i = 0; i < 8; ++i) {
                u16 hb = f2bf(xv[i]);
                hi8[i] = (short)hb;
                lo8[i] = (short)f2bf(xv[i] - bf2f(hb));
            }
            const int off = 4096 + (c * 4 + seg_m) * 512 + laneS * 8;
            *(s16x8*)(sm + off)        = hi8;
            *(s16x8*)(sm + off + 8192) = lo8;
        }
    }
    __syncthreads();

    // ---- Phase B: gate-x GEMM (R0 Smean) + gate-h kt{0,1} (R1) ----
    f32x4 acc[2][4][4];
    #pragma unroll
    for (int mf = 0; mf < 2; ++mf)
        #pragma unroll
        for (int g = 0; g < 4; ++g)
            #pragma unroll
            for (int t4 = 0; t4 < 4; ++t4)
                acc[mf][g][t4] = (f32x4){0.f, 0.f, 0.f, 0.f};

    {
        const s16x8* Bx8 = (const s16x8*)BxH;
        const s16x8* Bxl8 = (const s16x8*)BxL;
        const s16x8* Bh8 = (const s16x8*)BhH;
        const s16x8* Bhl8 = (const s16x8*)BhL;
        #pragma unroll
        for (int kt = 0; kt < 2; ++kt) {
            // gate-x from R0
            {
                const int a0off = (kt * 4 + 2 * mh) * 512 + lane * 8;
                const s16x8 aH0 = *(const s16x8*)(sm + a0off);
                const s16x8 aL0 = *(const s16x8*)(sm + 8192 + a0off);
                const s16x8 aH1 = *(const s16x8*)(sm + a0off + 512);
                const s16x8 aL1 = *(const s16x8*)(sm + 8192 + a0off + 512);
                #pragma unroll
                for (int g = 0; g < 3; ++g) {      // z, r, xh
                    #pragma unroll
                    for (int t4 = 0; t4 < 4; ++t4) {
                        const int idx = (kt * 24 + g * 8 + jg * 4 + t4) * 64 + lane;
                        const s16x8 bH = Bx8[idx];
                        const s16x8 bL = Bxl8[idx];
                        acc[0][g][t4] = __builtin_amdgcn_mfma_f32_16x16x32_bf16(aH0, bH, acc[0][g][t4], 0, 0, 0);
                        acc[0][g][t4] = __builtin_amdgcn_mfma_f32_16x16x32_bf16(aH0, bL, acc[0][g][t4], 0, 0, 0);
                        acc[0][g][t4] = __builtin_amdgcn_mfma_f32_16x16x32_bf16(aL0, bH, acc[0][g][t4], 0, 0, 0);
                        acc[1][g][t4] = __builtin_amdgcn_mfma_f32_16x16x32_bf16(aH1, bH, acc[1][g][t4], 0, 0, 0);
                        acc[1][g][t4] = __builtin_amdgcn_mfma_f32_16x16x32_bf16(aH1, bL, acc[1][g][t4], 0, 0, 0);
                        acc[1][g][t4] = __builtin_amdgcn_mfma_f32_16x16x32_bf16(aL1, bH, acc[1][g][t4], 0, 0, 0);
                    }
                }
            }
            // gate-h kt (0,1) from R1
            {
                const int a0off = 4096 + (kt * 4 + 2 * mh) * 512 + lane * 8;
                const s16x8 aH0 = *(const s16x8*)(sm + a0off);
                const s16x8 aL0 = *(const s16x8*)(sm + 8192 + a0off);
                const s16x8 aH1 = *(const s16x8*)(sm + a0off + 512);
                const s16x8 aL1 = *(const s16x8*)(sm + 8192 + a0off + 512);
                #pragma unroll
                for (int s = 0; s < 3; ++s) {
                    const int g = (s == 2) ? 3 : s;   // z, r, hh
                    #pragma unroll
                    for (int t4 = 0; t4 < 4; ++t4) {
                        const int idx = (kt * 24 + s * 8 + jg * 4 + t4) * 64 + lane;
                        const s16x8 bH = Bh8[idx];
                        const s16x8 bL = Bhl8[idx];
                        acc[0][g][t4] = __builtin_amdgcn_mfma_f32_16x16x32_bf16(aH0, bH, acc[0][g][t4], 0, 0, 0);
                        acc[0][g][t4] = __builtin_amdgcn_mfma_f32_16x16x32_bf16(aH0, bL, acc[0][g][t4], 0, 0, 0);
                        acc[0][g][t4] = __builtin_amdgcn_mfma_f32_16x16x32_bf16(aL0, bH, acc[0][g][t4], 0, 0, 0);
                        acc[1][g][t4] = __builtin_amdgcn_mfma_f32_16x16x32_bf16(aH1, bH, acc[1][g][t4], 0, 0, 0);
                        acc[1][g][t4] = __builtin_amdgcn_mfma_f32_16x16x32_bf16(aH1, bL, acc[1][g][t4], 0, 0, 0);
                        acc[1][g][t4] = __builtin_amdgcn_mfma_f32_16x16x32_bf16(aL1, bH, acc[1][g][t4], 0, 0, 0);
                    }
                }
            }
        }
    }
    __syncthreads();   // Smean reads done; R0 reused for h k-half1

    // ---- Phase C: stage h k-half1 -> R0 ----
    #pragma unroll
    for (int c = 2; c < 4; ++c) {
        const int kl = c * 32 + q * 8;
        const float* src = hio + (size_t)nodeS * DDIM + kl;
        const float4 v0 = ((const float4*)src)[0];
        const float4 v1 = ((const float4*)src)[1];
        float xv[8] = { v0.x, v0.y, v0.z, v0.w, v1.x, v1.y, v1.z, v1.w };
        s16x8 hi8, lo8;
        #pragma unroll
        for (int i = 0; i < 8; ++i) {
            u16 hb = f2bf(xv[i]);
            hi8[i] = (short)hb;
            lo8[i] = (short)f2bf(xv[i] - bf2f(hb));
        }
        const int off = ((c - 2) * 4 + seg_m) * 512 + laneS * 8;
        *(s16x8*)(sm + off)        = hi8;
        *(s16x8*)(sm + off + 8192) = lo8;
    }
    __syncthreads();

    // ---- Phase D: gate-h kt{2,3} from R0 ----
    {
        const s16x8* Bh8 = (const s16x8*)BhH;
        const s16x8* Bhl8 = (const s16x8*)BhL;
        #pragma unroll
        for (int kt = 2; kt < 4; ++kt) {
            const int a0off = ((kt - 2) * 4 + 2 * mh) * 512 + lane * 8;
            const s16x8 aH0 = *(const s16x8*)(sm + a0off);
            const s16x8 aL0 = *(const s16x8*)(sm + 8192 + a0off);
            const s16x8 aH1 = *(const s16x8*)(sm + a0off + 512);
            const s16x8 aL1 = *(const s16x8*)(sm + 8192 + a0off + 512);
            #pragma unroll
            for (int s = 0; s < 3; ++s) {
                const int g = (s == 2) ? 3 : s;   // z, r, hh
                #pragma unroll
                for (int t4 = 0; t4 < 4; ++t4) {
                    const int idx = (kt * 24 + s * 8 + jg * 4 + t4) * 64 + lane;
                    const s16x8 bH = Bh8[idx];
                    const s16x8 bL = Bhl8[idx];
                    acc[0][g][t4] = __builtin_amdgcn_mfma_f32_16x16x32_bf16(aH0, bH, acc[0][g][t4], 0, 0, 0);
                    acc[0][g][t4] = __builtin_amdgcn_mfma_f32_16x16x32_bf16(aH0, bL, acc[0][g][t4], 0, 0, 0);
                    acc[0][g][t4] = __builtin_amdgcn_mfma_f32_16x16x32_bf16(aL0, bH, acc[0][g][t4], 0, 0, 0);
                    acc[1][g][t4] = __builtin_amdgcn_mfma_f32_16x16x32_bf16(aH1, bH, acc[1][g][t4], 0, 0, 0);
                    acc[1][g][t4] = __builtin_amdgcn_mfma_f32_16x16x32_bf16(aH1, bL, acc[1][g][t4], 0, 0, 0);
                    acc[1][g][t4] = __builtin_amdgcn_mfma_f32_16x16x32_bf16(aL1, bH, acc[1][g][t4], 0, 0, 0);
                }
            }
        }
    }

    // ---- Phase E: epilogue -> h' (hv region by jg: 0->R1, 1->R0) ----
    bool bon[2][4];
    #pragma unroll
    for (int mf = 0; mf < 2; ++mf)
        #pragma unroll
        for (int r = 0; r < 4; ++r)
            bon[mf][r] = deg[nbase + (2 * mh + mf) * 16 + (lane >> 4) * 4 + r] > 0;

    const int regbase = jg ? 0 : 4096;
    float hn[2][4][4];
    #pragma unroll
    for (int t4 = 0; t4 < 4; ++t4) {
        const int j = jg * 64 + t4 * 16 + (lane & 15);
        const int jj = j & 63;
        const float b_az = bi_[j]       + br_[j];
        const float b_ar = bi_[128 + j] + br_[128 + j];
        const float b_xh = bi_[256 + j];
        const float b_hh = br_[256 + j];
        const float bcz = bc[j];
        const float bcr = bc[128 + j];
        const float bcx = bc[256 + j];
        const int jbase = regbase + (jj >> 5) * 2048 + ((jj >> 3) & 3) * 128 + (jj & 7);
        #pragma unroll
        for (int mf = 0; mf < 2; ++mf) {
            const int mtile = 2 * mh + mf;
            #pragma unroll
            for (int r = 0; r < 4; ++r) {
                const int m15 = (lane >> 4) * 4 + r;
                const int off = jbase + mtile * 512 + m15 * 8;
                const float hv = bf2f((u16)sm[off]) + bf2f((u16)sm[8192 + off]);
                const int m = mtile * 16 + m15;
                const float bsel = bon[mf][r] ? 1.0f : 0.0f;
                const float az = acc[mf][0][t4][r] + b_az + bsel * bcz;
                const float ar = acc[mf][1][t4][r] + b_ar + bsel * bcr;
                const float xh = acc[mf][2][t4][r] + b_xh + bsel * bcx;
                const float hh = acc[mf][3][t4][r] + b_hh;
                const float z    = sigmoid_fast(az);
                const float rr   = sigmoid_fast(ar);
                const float cand = tanh_fast(xh + rr * hh);
                const float v    = z * hv + (1.0f - z) * cand;
                hio[(size_t)(nbase + m) * DDIM + j] = v;
                hn[mf][t4][r] = v;
            }
        }
    }
    __syncthreads();   // h-frag LDS reads done; reuse sm for pre-A frags

    // ---- Phase F: scatter h' into node_pre A-frag layout ----
    #pragma unroll
    for (int mf = 0; mf < 2; ++mf) {
        const int mtile = 2 * mh + mf;
        #pragma unroll
        for (int t4 = 0; t4 < 4; ++t4) {
            #pragma unroll
            for (int r = 0; r < 4; ++r) {
                const int m15 = (lane >> 4) * 4 + r;
                const int j   = jg * 64 + t4 * 16 + (lane & 15);
                const int kt2 = j >> 5, gg = (j >> 3) & 3, jj = j & 7;
                const int off = (kt2 * 4 + mtile) * 512 + (m15 + 16 * gg) * 8 + jj;
                const float v = hn[mf][t4][r];
                u16 hb = f2bf(v);
                sm[off]        = (short)hb;
                sm[off + 8192] = (short)f2bf(v - bf2f(hb));
            }
        }
    }
    __syncthreads();

    // ---- Phase G: node_pre GEMM -> p ----
    f32x4 acc2[2][4];
    #pragma unroll
    for (int mf = 0; mf < 2; ++mf)
        #pragma unroll
        for (int t4 = 0; t4 < 4; ++t4)
            acc2[mf][t4] = (f32x4){0.f, 0.f, 0.f, 0.f};

    const s16x8* Ph8 = (const s16x8*)BpH;
    const s16x8* Pl8 = (const s16x8*)BpL;
    #pragma unroll
    for (int kt2 = 0; kt2 < 4; ++kt2) {
        const int a0off = (kt2 * 4 + 2 * mh) * 512 + lane * 8;
        const s16x8 aH0 = *(const s16x8*)(sm + a0off);
        const s16x8 aL0 = *(const s16x8*)(sm + 8192 + a0off);
        const s16x8 aH1 = *(const s16x8*)(sm + a0off + 512);
        const s16x8 aL1 = *(const s16x8*)(sm + 8192 + a0off + 512);
        #pragma unroll
        for (int t4 = 0; t4 < 4; ++t4) {
            const int idx = (kt2 * 8 + jg * 4 + t4) * 64 + lane;
            const s16x8 bH = Ph8[idx];
            const s16x8 bL = Pl8[idx];
            acc2[0][t4] = __builtin_amdgcn_mfma_f32_16x16x32_bf16(aH0, bH, acc2[0][t4], 0, 0, 0);
            acc2[0][t4] = __builtin_amdgcn_mfma_f32_16x16x32_bf16(aH0, bL, acc2[0][t4], 0, 0, 0);
            acc2[0][t4] = __builtin_amdgcn_mfma_f32_16x16x32_bf16(aL0, bH, acc2[0][t4], 0, 0, 0);
            acc2[1][t4] = __builtin_amdgcn_mfma_f32_16x16x32_bf16(aH1, bH, acc2[1][t4], 0, 0, 0);
            acc2[1][t4] = __builtin_amdgcn_mfma_f32_16x16x32_bf16(aH1, bL, acc2[1][t4], 0, 0, 0);
            acc2[1][t4] = __builtin_amdgcn_mfma_f32_16x16x32_bf16(aL1, bH, acc2[1][t4], 0, 0, 0);
        }
    }
    __syncthreads();   // pre-frag reads done before f32 overlay

    // p -> f32 overlay (stride 130 floats, bank-safe), then coalesced store
    {
        float* pf = (float*)sm;
        #pragma unroll
        for (int mf = 0; mf < 2; ++mf) {
            const int mtile = 2 * mh + mf;
            #pragma unroll
            for (int t4 = 0; t4 < 4; ++t4) {
                const int n = jg * 64 + t4 * 16 + (lane & 15);
                const float badd = (n < 64) ? binp[n] : 0.0f;
                #pragma unroll
                for (int r = 0; r < 4; ++r) {
                    const int m = mtile * 16 + (lane >> 4) * 4 + r;
                    pf[m * 130 + n] = acc2[mf][t4][r] + badd;
                }
            }
        }
        __syncthreads();
        const int prow = tid >> 2, pcol = (tid & 3) * 32;
        float4* dst = (float4*)(pout + (size_t)(nbase + prow) * DDIM + pcol);
        const float* srcr = pf + prow * 130 + pcol;
        #pragma unroll
        for (int qq = 0; qq < 8; ++qq)
            dst[qq] = make_float4(srcr[qq*4], srcr[qq*4+1], srcr[qq*4+2], srcr[qq*4+3]);
    }
}

// Readout: block=64, LDS activation slices, scalar weights.
__global__ __launch_bounds__(64) void readout_kernel(
    const float* __restrict__ h,
    const float* __restrict__ Win,  const float* __restrict__ bin,
    const float* __restrict__ Whid, const float* __restrict__ bhid,
    const float* __restrict__ Wout, const float* __restrict__ bout,
    float* __restrict__ out)
{
    __shared__ float xs[64 * 65];
    const int tid = threadIdx.x;
    const int row = blockIdx.x * 64 + tid;
    const int b = row / 1000, n = row % 1000;
    const float4* xrow = (const float4*)(h + ((size_t)b * 4000 + n) * DDIM);

    {
        float acc[64];
        #pragma unroll
        for (int j = 0; j < 64; ++j) acc[j] = bin[j];
        #pragma unroll 2
        for (int k4 = 0; k4 < 32; ++k4) {
            float4 xv = xrow[k4];
            #pragma unroll
            for (int kk = 0; kk < 4; ++kk) {
                const float xk = (&xv.x)[kk];
                const float* wr = Win + (size_t)(k4 * 4 + kk) * 64;
                #pragma unroll
                for (int j = 0; j < 64; ++j) acc[j] = fmaf(xk, wr[j], acc[j]);
            }
        }
        #pragma unroll
        for (int j = 0; j < 64; ++j) xs[tid * 65 + j] = gelu_fast(acc[j]);
    }

    for (int L = 0; L < 3; ++L) {
        float acc[64];
        #pragma unroll
        for (int j = 0; j < 64; ++j) acc[j] = bhid[L * 64 + j];
        #pragma unroll 4
        for (int k = 0; k < 64; ++k) {
            const float xk = xs[tid * 65 + k];
            const float* wr = Whid + (size_t)L * 4096 + (size_t)k * 64;
            #pragma unroll
            for (int j = 0; j < 64; ++j) acc[j] = fmaf(xk, wr[j], acc[j]);
        }
        #pragma unroll
        for (int j = 0; j < 64; ++j) xs[tid * 65 + j] = gelu_fast(acc[j]);
    }

    float acc[10];
    #pragma unroll
    for (int pj = 0; pj < 10; ++pj) acc[pj] = bout[pj];
    #pragma unroll 4
    for (int k = 0; k < 64; ++k) {
        const float xk = xs[tid * 65 + k];
        const float* wr = Wout + k * 10;
        #pragma unroll
        for (int pj = 0; pj < 10; ++pj) acc[pj] = fmaf(xk, wr[pj], acc[pj]);
    }
    #pragma unroll
    for (int pj = 0; pj < 10; ++pj) out[(size_t)row * 10 + pj] = acc[pj];
}

extern "C" void kernel_launch(void* const* d_in, const int* in_sizes, int n_in,
                              void* d_out, int out_size, void* d_ws, size_t ws_size,
                              hipStream_t stream) {
    const int*   node_inputs = (const int*)d_in[0];
    const int*   ni_int = (const int*)d_in[1];
    const int*   bi_int = (const int*)d_in[2];
    const int*   ni_tmp = (const int*)d_in[3];
    const int*   bi_tmp = (const int*)d_in[4];
    const float* embed  = (const float*)d_in[5];
    const float* mWin   = (const float*)d_in[6];
    const float* mbin   = (const float*)d_in[7];
    const float* mWhid  = (const float*)d_in[8];
    const float* mbhid  = (const float*)d_in[9];
    const float* mWout  = (const float*)d_in[10];
    const float* mbout  = (const float*)d_in[11];
    const float* roWin  = (const float*)d_in[12];
    const float* robin  = (const float*)d_in[13];
    const float* roWhid = (const float*)d_in[14];
    const float* robhid = (const float*)d_in[15];
    const float* roWout = (const float*)d_in[16];
    const float* robout = (const float*)d_in[17];
    const float* giWx = (const float*)d_in[18];
    const float* giWh = (const float*)d_in[19];
    const float* gibi = (const float*)d_in[20];
    const float* gibr = (const float*)d_in[21];
    const float* gtWx = (const float*)d_in[22];
    const float* gtWh = (const float*)d_in[23];
    const float* gtbi = (const float*)d_in[24];
    const float* gtbr = (const float*)d_in[25];
    float* out = (float*)d_out;

    const int E_INT = 200000, E_TMP = 96000;
    const int NSLOT_I = 400000;   // 3125*128 exact
    const int NSLOT_T = 192000;   // 1500*128 exact
    const int NBLK_I = NSLOT_I / EBLK;
    const int NBLK_T = NSLOT_T / EBLK;
    const int NS32_I = NSLOT_I / 32;   // 12500
    const int NS32_T = NSLOT_T / 32;   // 6000

    char* ws = (char*)d_ws;
    float* B0 = (float*)(ws);                 // h (in-place)
    float* B1 = (float*)(ws + HBYTES);        // p
    float* B2 = (float*)(ws + 2 * HBYTES);    // S (64-wide)
    char*  ib = ws + 3 * HBYTES;

    int* deg_i   = (int*)(ib);
    int* deg_t   = (int*)(ib + 512000);
    int* offp_i  = (int*)(ib + 1024000);
    int* offp_t  = (int*)(ib + 1536000);
    int* bexc_i  = (int*)(ib + 2048000);
    int* bexc_t  = (int*)(ib + 2052096);
    int* bsum    = (int*)(ib + 2056192);
    int* cursor  = (int*)(ib + 2060288);
    int* el_i    = (int*)(ib + 2572288);
    int* el_t    = (int*)(ib + 4172288);
    int* ssi_raw = (int*)(ib + 4940288);
    int* sst_raw = (int*)(ib + 6540296);
    // packed-weight buffers (R28 layout)
    char* fb = ib + 8114176;
    u16* BxiH = (u16*)(fb);               // 49152 B
    u16* BxiL = (u16*)(fb +  49152);
    u16* BhiH = (u16*)(fb +  98304);      // 98304 B
    u16* BhiL = (u16*)(fb + 196608);
    u16* BxtH = (u16*)(fb + 294912);
    u16* BxtL = (u16*)(fb + 344064);
    u16* BhtH = (u16*)(fb + 393216);
    u16* BhtL = (u16*)(fb + 491520);
    float* bci = (float*)(fb + 589824);   // 1536 B
    float* bct = (float*)(fb + 591360);
    u16* BpH  = (u16*)(fb + 592896);      // 32768 B
    u16* BpL  = (u16*)(fb + 625664);
    u16* EhH  = (u16*)(fb + 658432);      // 24576 B
    u16* EhL  = (u16*)(fb + 683008);
    int* str_i  = (int*)(fb + 707584);    // up to 12500 ints
    int* str_t  = (int*)(fb + 757584);    // up to 6000 ints
    int* strc_i = (int*)(fb + 781584);
    int* strc_t = (int*)(fb + 781588);
    int* ssi = ssi_raw + 1;
    int* sst = sst_raw + 1;

    embed_kernel<<<16000, 256, 0, stream>>>(node_inputs, embed, B0);

    hipMemsetAsync(deg_i, 0, NTOT * sizeof(int), stream);
    hipMemsetAsync(deg_t, 0, NTOT * sizeof(int), stream);
    hist_kernel<<<(2 * E_INT + 255) / 256, 256, 0, stream>>>(ni_int, bi_int, E_INT, deg_i);
    hist_kernel<<<(2 * E_TMP + 255) / 256, 256, 0, stream>>>(ni_tmp, bi_tmp, E_TMP, deg_t);

    hipMemsetAsync(ssi_raw, 0xFF, (size_t)(NSLOT_I + 2) * sizeof(int), stream);
    hipMemsetAsync(sst_raw, 0xFF, (size_t)(NSLOT_T + 2) * sizeof(int), stream);

    blockscan_kernel<<<500, 256, 0, stream>>>(deg_i, offp_i, bsum);
    bscan_kernel<<<1, 512, 0, stream>>>(bsum, bexc_i, 500);
    hipMemsetAsync(cursor, 0, NTOT * sizeof(int), stream);
    fill_kernel<<<(2 * E_INT + 255) / 256, 256, 0, stream>>>(
        ni_int, bi_int, E_INT, offp_i, bexc_i, cursor, el_i, ssi);

    blockscan_kernel<<<500, 256, 0, stream>>>(deg_t, offp_t, bsum);
    bscan_kernel<<<1, 512, 0, stream>>>(bsum, bexc_t, 500);
    hipMemsetAsync(cursor, 0, NTOT * sizeof(int), stream);
    fill_kernel<<<(2 * E_TMP + 255) / 256, 256, 0, stream>>>(
        ni_tmp, bi_tmp, E_TMP, offp_t, bexc_t, cursor, el_t, sst);

    hipMemsetAsync(strc_i, 0, sizeof(int), stream);
    hipMemsetAsync(strc_t, 0, sizeof(int), stream);
    straddle_kernel<<<(NS32_I + 255) / 256, 256, 0, stream>>>(ssi, NS32_I, str_i, strc_i);
    straddle_kernel<<<(NS32_T + 255) / 256, 256, 0, stream>>>(sst, NS32_T, str_t, strc_t);

    pack_gateBx_kernel<<<96, 256, 0, stream>>>(mWout, giWx, BxiH, BxiL);
    pack_gateBx_kernel<<<96, 256, 0, stream>>>(mWout, gtWx, BxtH, BxtL);
    pack_gateBh_kernel<<<192, 256, 0, stream>>>(giWh, BhiH, BhiL);
    pack_gateBh_kernel<<<192, 256, 0, stream>>>(gtWh, BhtH, BhtL);
    pack_gbias_kernel<<<2, 256, 0, stream>>>(mbout, giWx, bci);
    pack_gbias_kernel<<<2, 256, 0, stream>>>(mbout, gtWx, bct);
    pack_preB_kernel<<<64, 256, 0, stream>>>(mWin, BpH, BpL);
    pack_hidB_kernel<<<48, 256, 0, stream>>>(mWhid, EhH, EhL);

    node_pre_mfma<<<NTOT / 128, 512, 0, stream>>>(B0, BpH, BpL, mbin, B1);

    // fixed roles: h=B0 (in place), p=B1, S=B2
    for (int ph = 0; ph < 4; ++ph) {
        const bool isInt = (ph % 2 == 0);
        if (isInt) {
            zero_rows_kernel<<<NS32_I, 64, 0, stream>>>(str_i, strc_i, B2);
            edge_mlp_mfma<<<NBLK_I, 512, 0, stream>>>(
                ni_int, bi_int, E_INT, el_i, ssi, B1,
                EhH, EhL, mbhid, B2);
            gru_mfma_kernel<<<NTOT / 64, 256, 0, stream>>>(
                B0, B2, deg_i, BxiH, BxiL, BhiH, BhiL, bci,
                gibi, gibr, BpH, BpL, mbin, B1);
        } else {
            zero_rows_kernel<<<NS32_T, 64, 0, stream>>>(str_t, strc_t, B2);
            edge_mlp_mfma<<<NBLK_T, 512, 0, stream>>>(
                ni_tmp, bi_tmp, E_TMP, el_t, sst, B1,
                EhH, EhL, mbhid, B2);
            gru_mfma_kernel<<<NTOT / 64, 256, 0, stream>>>(
                B0, B2, deg_t, BxtH, BxtL, BhtH, BhtL, bct,
                gtbi, gtbr, BpH, BpL, mbin, B1);
        }
    }

    readout_kernel<<<500, 64, 0, stream>>>(
        B0, roWin, robin, roWhid, robhid, roWout, robout, out);
}

// Round 11
// 1246.273 us; speedup vs baseline: 1.0544x; 1.0544x over previous
//
#include <hip/hip_runtime.h>
#include <math.h>

// MPNN on MI355X. R30 = exact revert to R28 (best: 1259us).
// R29 post-mortem: both changes regressed (gru 148->171us). (1) merged
// Smean+h-half0 staging split each h row read across two phases ->
// FETCH 88->124MB; (2) p write via LDS f32 overlay -> WRITE 208->287MB,
// bank conflicts 4.35M->6.4M. Reverted both.
// R28 = composite-weight GRU: x@Wx = Smean@(Wout@Wx) + (bout@Wx)*1{deg>0}
// via precomputed C=Wout@Wx, bc=bout@Wx. 528 MFMA/wave, 5 barriers.
// Validated constraint ledger:
//  - gru (256,3) = VGPR ceiling (R26: (256,4) forces 64 VGPR -> spills).
//  - 64-node/2000-block grid (R25: 128-node halves parallelism, net loss).
//  - no stall-merge / LDS write staging (R29: both regress).
//  - edge/CSR/straddle/node_pre_mfma/readout: validated since R24-R27.

#define DDIM 128
#define NTOT 128000
#define HBYTES 65536000ULL   // 128000*128*4
#define EBLK 128

typedef unsigned short u16;
using f32x4 = __attribute__((ext_vector_type(4))) float;
using s16x8 = __attribute__((ext_vector_type(8))) short;

__device__ __forceinline__ float fast_rcp(float x) {
    return __builtin_amdgcn_rcpf(x);
}
// A&S 7.1.26 erf, |abs err| <= 1.5e-7; raw v_rcp (1 ulp) for the divide.
__device__ __forceinline__ float gelu_fast(float x) {
    const float ax = fabsf(x) * 0.70710678118654752440f;
    const float t  = fast_rcp(1.0f + 0.3275911f * ax);
    const float poly = t * (0.254829592f + t * (-0.284496736f +
                       t * (1.421413741f + t * (-1.453152027f +
                       t * 1.061405429f))));
    const float e = __expf(-ax * ax);
    const float erfax = 1.0f - poly * e;
    const float erfv = copysignf(erfax, x);
    return 0.5f * x * (1.0f + erfv);
}
__device__ __forceinline__ float sigmoid_fast(float x) {
    return fast_rcp(1.0f + __expf(-x));
}
__device__ __forceinline__ float tanh_fast(float x) {
    const float e = __expf(2.0f * x);     // tanh = 1 - 2/(e^{2x}+1)
    return 1.0f - 2.0f * fast_rcp(e + 1.0f);
}
__device__ __forceinline__ u16 f2bf(float x) {            // RNE f32->bf16
    unsigned u = __float_as_uint(x);
    u += 0x7fffu + ((u >> 16) & 1u);
    return (u16)(u >> 16);
}
__device__ __forceinline__ float bf2f(u16 h) {
    return __uint_as_float(((unsigned)h) << 16);
}

__global__ __launch_bounds__(256) void embed_kernel(
    const int* __restrict__ inp, const float* __restrict__ table,
    float* __restrict__ h)
{
    int gid = blockIdx.x * 256 + threadIdx.x;
    if (gid >= NTOT * 32) return;
    int row = gid >> 5;
    int q   = gid & 31;
    int b   = row / 4000;
    int n   = (row % 4000) % 1000;
    int e   = inp[b * 1000 + n];
    ((float4*)h)[gid] = ((const float4*)table)[e * 32 + q];
}

__global__ __launch_bounds__(256) void hist_kernel(
    const int* __restrict__ ni, const int* __restrict__ bi, int E,
    int* __restrict__ deg)
{
    int g = blockIdx.x * 256 + threadIdx.x;
    if (g < E)          atomicAdd(&deg[bi[g]], 1);
    else if (g < 2 * E) atomicAdd(&deg[ni[g - E]], 1);
}

__global__ __launch_bounds__(256) void blockscan_kernel(
    const int* __restrict__ deg, int* __restrict__ offp, int* __restrict__ bsum)
{
    __shared__ int s[256];
    int tid = threadIdx.x;
    int i = blockIdx.x * 256 + tid;
    int v = deg[i];
    s[tid] = v;
    __syncthreads();
    for (int off = 1; off < 256; off <<= 1) {
        int t = (tid >= off) ? s[tid - off] : 0;
        __syncthreads();
        s[tid] += t;
        __syncthreads();
    }
    offp[i] = s[tid] - v;
    if (tid == 255) bsum[blockIdx.x] = s[255];
}

__global__ __launch_bounds__(512) void bscan_kernel(
    const int* __restrict__ bsum, int* __restrict__ bexc, int nb)
{
    __shared__ int s[512];
    int t = threadIdx.x;
    int v = (t < nb) ? bsum[t] : 0;
    s[t] = v;
    __syncthreads();
    for (int off = 1; off < 512; off <<= 1) {
        int u = (t >= off) ? s[t - off] : 0;
        __syncthreads();
        s[t] += u;
        __syncthreads();
    }
    if (t < nb) bexc[t] = s[t] - v;
}

__global__ __launch_bounds__(256) void fill_kernel(
    const int* __restrict__ ni, const int* __restrict__ bi, int E,
    const int* __restrict__ offp, const int* __restrict__ bexc,
    int* __restrict__ cursor, int* __restrict__ elist, int* __restrict__ slotseg)
{
    int g = blockIdx.x * 256 + threadIdx.x;
    if (g >= 2 * E) return;
    int seg = (g < E) ? bi[g] : ni[g - E];
    int pos = atomicAdd(&cursor[seg], 1);
    int slot = offp[seg] + bexc[seg >> 8] + pos;
    elist[slot] = g;
    slotseg[slot] = seg;
}

// Segments straddling a 32-slot boundary — the only atomicAdd targets.
__global__ __launch_bounds__(256) void straddle_kernel(
    const int* __restrict__ slotseg, int nblocks32,
    int* __restrict__ list, int* __restrict__ count)
{
    int b = blockIdx.x * 256 + threadIdx.x + 1;
    if (b >= nblocks32) return;
    int s = slotseg[b * 32];
    if (s >= 0 && slotseg[b * 32 - 1] == s) {
        int pos = atomicAdd(count, 1);
        list[pos] = s;
    }
}

__global__ __launch_bounds__(64) void zero_rows_kernel(
    const int* __restrict__ list, const int* __restrict__ count,
    float* __restrict__ sbuf)   // 64-wide rows
{
    int i = blockIdx.x;
    if (i >= *count) return;
    int seg = list[i];
    float4* row = (float4*)(sbuf + (size_t)seg * 64);
    if (threadIdx.x < 16) row[threadIdx.x] = make_float4(0.f, 0.f, 0.f, 0.f);
}

// ---------------------------------------------------------------------------
// B-fragment packers (run once per launch). Shared frag map:
// lane l, elem j -> k = kt*32+(l>>4)*8+j, n = nt*16+(l&15).
// ---------------------------------------------------------------------------

// Composite gate-x B: C = Wout[64x128] @ Wx[128x384], slots z|r|xh.
// idx = (kt*24 + g*8 + nt)*512 + lane*8 + j; kt in {0,1}, g in {0,1,2}.
__global__ __launch_bounds__(256) void pack_gateBx_kernel(
    const float* __restrict__ Wout, const float* __restrict__ Wx,
    u16* __restrict__ BH, u16* __restrict__ BL)
{
    int idx = blockIdx.x * 256 + threadIdx.x;   // 24576 total
    if (idx >= 24576) return;
    int j    = idx & 7;
    int lane = (idx >> 3) & 63;
    int tile = idx >> 9;
    int nt   = tile & 7;
    int g    = (tile >> 3) % 3;
    int kt   = tile / 24;                        // 0..1
    int k   = kt * 32 + (lane >> 4) * 8 + j;     // 0..63
    int col = g * 128 + nt * 16 + (lane & 15);   // 0..383
    float acc = 0.0f;
    for (int t = 0; t < 128; ++t)
        acc = fmaf(Wout[k * 128 + t], Wx[t * 384 + col], acc);
    u16 hb = f2bf(acc);
    BH[idx] = hb;
    BL[idx] = f2bf(acc - bf2f(hb));
}

// Gate-h B: Wh[128x384], slots z|r|hh (cols 0|128|256).
// idx = (kt*24 + s*8 + nt)*512 + lane*8 + j; kt in {0..3}, s in {0,1,2}.
__global__ __launch_bounds__(256) void pack_gateBh_kernel(
    const float* __restrict__ Wh, u16* __restrict__ BH, u16* __restrict__ BL)
{
    int idx = blockIdx.x * 256 + threadIdx.x;   // 49152 total
    if (idx >= 49152) return;
    int j    = idx & 7;
    int lane = (idx >> 3) & 63;
    int tile = idx >> 9;
    int nt   = tile & 7;
    int s    = (tile >> 3) % 3;
    int kt   = tile / 24;                        // 0..3
    int k    = kt * 32 + (lane >> 4) * 8 + j;    // 0..127
    int col  = ((s == 2) ? 256 : s * 128) + nt * 16 + (lane & 15);
    float v = Wh[k * 384 + col];
    u16 hb = f2bf(v);
    BH[idx] = hb;
    BL[idx] = f2bf(v - bf2f(hb));
}

// Composite gate bias: bc[n] = sum_t bout[t] * Wx[t*384+n], n in [0,384).
__global__ __launch_bounds__(256) void pack_gbias_kernel(
    const float* __restrict__ bout, const float* __restrict__ Wx,
    float* __restrict__ bc)
{
    int n = blockIdx.x * 256 + threadIdx.x;
    if (n >= 384) return;
    float acc = 0.0f;
    for (int t = 0; t < 128; ++t)
        acc = fmaf(bout[t], Wx[t * 384 + n], acc);
    bc[n] = acc;
}

// node_pre B: [K=128][N=128], n<64 -> Win rows 0..127, n>=64 -> rows 128..255.
__global__ __launch_bounds__(256) void pack_preB_kernel(
    const float* __restrict__ Win, u16* __restrict__ BH, u16* __restrict__ BL)
{
    int idx = blockIdx.x * 256 + threadIdx.x;   // 16384 total
    if (idx >= 16384) return;
    int j    = idx & 7;
    int lane = (idx >> 3) & 63;
    int nt2  = (idx >> 9) & 7;
    int kt2  = idx >> 12;                        // 0..3
    int k = kt2 * 32 + (lane >> 4) * 8 + j;      // 0..127
    int n = nt2 * 16 + (lane & 15);              // 0..127
    float v = (n < 64) ? Win[k * 64 + n] : Win[(128 + k) * 64 + (n - 64)];
    u16 hb = f2bf(v);
    BH[idx] = hb;
    BL[idx] = f2bf(v - bf2f(hb));
}

// Edge-MLP hidden B: 3 layers x [K=64][N=64]. idx=(L*8+kt*4+nt)*512+lane*8+j.
__global__ __launch_bounds__(256) void pack_hidB_kernel(
    const float* __restrict__ Whid, u16* __restrict__ BH, u16* __restrict__ BL)
{
    int idx = blockIdx.x * 256 + threadIdx.x;   // 12288 total
    if (idx >= 12288) return;
    int j    = idx & 7;
    int lane = (idx >> 3) & 63;
    int nt   = (idx >> 9) & 3;
    int kt   = (idx >> 11) & 1;
    int L    = idx >> 12;
    int k = kt * 32 + (lane >> 4) * 8 + j;       // 0..63
    int n = nt * 16 + (lane & 15);               // 0..63
    float v = Whid[L * 4096 + k * 64 + n];
    u16 hb = f2bf(v);
    BH[idx] = hb;
    BL[idx] = f2bf(v - bf2f(hb));
}

// ---------------------------------------------------------------------------
// Initial p via MFMA (validated R25-R28). 128 nodes / 512 thr / 8 waves.
// ---------------------------------------------------------------------------
__global__ __launch_bounds__(512, 2) void node_pre_mfma(
    const float* __restrict__ h,
    const u16* __restrict__ BpH, const u16* __restrict__ BpL,
    const float* __restrict__ binp, float* __restrict__ pout)
{
    __shared__ short sm[32768];   // hi [0,16384), lo [16384,32768) shorts
    const int tid  = threadIdx.x;
    const int lane = tid & 63;
    const int w    = tid >> 6;    // 0..7
    const int jg   = w & 1;
    const int mh   = w >> 1;      // 0..3
    const int nbase = blockIdx.x * 128;

    const int mS = tid >> 2, q = tid & 3;
    const int nodeS = nbase + mS;
    const int laneS = (mS & 15) + 16 * q;
    const int seg_m = mS >> 4;

    #pragma unroll
    for (int c = 0; c < 4; ++c) {
        const int kl = c * 32 + q * 8;
        const float* src = h + (size_t)nodeS * DDIM + kl;
        const float4 v0 = ((const float4*)src)[0];
        const float4 v1 = ((const float4*)src)[1];
        float xv[8] = { v0.x, v0.y, v0.z, v0.w, v1.x, v1.y, v1.z, v1.w };
        s16x8 hi8, lo8;
        #pragma unroll
        for (int i = 0; i < 8; ++i) {
            u16 hb = f2bf(xv[i]);
            hi8[i] = (short)hb;
            lo8[i] = (short)f2bf(xv[i] - bf2f(hb));
        }
        const int off = (c * 8 + seg_m) * 512 + laneS * 8;
        *(s16x8*)(sm + off)         = hi8;
        *(s16x8*)(sm + off + 16384) = lo8;
    }
    __syncthreads();

    f32x4 acc2[2][4];
    #pragma unroll
    for (int mf = 0; mf < 2; ++mf)
        #pragma unroll
        for (int t4 = 0; t4 < 4; ++t4)
            acc2[mf][t4] = (f32x4){0.f, 0.f, 0.f, 0.f};

    const s16x8* Ph8 = (const s16x8*)BpH;
    const s16x8* Pl8 = (const s16x8*)BpL;
    #pragma unroll
    for (int kt2 = 0; kt2 < 4; ++kt2) {
        const int a0off = (kt2 * 8 + 2 * mh) * 512 + lane * 8;
        const s16x8 aH0 = *(const s16x8*)(sm + a0off);
        const s16x8 aL0 = *(const s16x8*)(sm + 16384 + a0off);
        const s16x8 aH1 = *(const s16x8*)(sm + a0off + 512);
        const s16x8 aL1 = *(const s16x8*)(sm + 16384 + a0off + 512);
        #pragma unroll
        for (int t4 = 0; t4 < 4; ++t4) {
            const int idx = (kt2 * 8 + jg * 4 + t4) * 64 + lane;
            const s16x8 bH = Ph8[idx];
            const s16x8 bL = Pl8[idx];
            acc2[0][t4] = __builtin_amdgcn_mfma_f32_16x16x32_bf16(aH0, bH, acc2[0][t4], 0, 0, 0);
            acc2[0][t4] = __builtin_amdgcn_mfma_f32_16x16x32_bf16(aH0, bL, acc2[0][t4], 0, 0, 0);
            acc2[0][t4] = __builtin_amdgcn_mfma_f32_16x16x32_bf16(aL0, bH, acc2[0][t4], 0, 0, 0);
            acc2[1][t4] = __builtin_amdgcn_mfma_f32_16x16x32_bf16(aH1, bH, acc2[1][t4], 0, 0, 0);
            acc2[1][t4] = __builtin_amdgcn_mfma_f32_16x16x32_bf16(aH1, bL, acc2[1][t4], 0, 0, 0);
            acc2[1][t4] = __builtin_amdgcn_mfma_f32_16x16x32_bf16(aL1, bH, acc2[1][t4], 0, 0, 0);
        }
    }
    #pragma unroll
    for (int mf = 0; mf < 2; ++mf) {
        const int mtile = 2 * mh + mf;
        #pragma unroll
        for (int t4 = 0; t4 < 4; ++t4) {
            const int n = jg * 64 + t4 * 16 + (lane & 15);
            const float badd = (n < 64) ? binp[n] : 0.0f;
            #pragma unroll
            for (int r = 0; r < 4; ++r) {
                const int m = mtile * 16 + (lane >> 4) * 4 + r;
                pout[(size_t)(nbase + m) * DDIM + n] = acc2[mf][t4][r] + badd;
            }
        }
    }
}

// ---------------------------------------------------------------------------
// MFMA edge MLP (R24, validated). 512 threads / 128 slots per block.
// ---------------------------------------------------------------------------
__global__ __launch_bounds__(512) void edge_mlp_mfma(
    const int* __restrict__ ni, const int* __restrict__ bi, int E,
    const int* __restrict__ elist, const int* __restrict__ slotseg,
    const float* __restrict__ p,
    const u16* __restrict__ BhH, const u16* __restrict__ BhL,
    const float* __restrict__ bhid,
    float* __restrict__ sbuf)
{
    __shared__ short smA[17408];      // 34816B; frags [0,16384) shorts
    __shared__ int   segLDS[EBLK];
    __shared__ int   segedge[2];
    float* scat = (float*)smA;

    const int tid  = threadIdx.x;
    const int lane = tid & 63;
    const int w    = tid >> 6;        // wave = m-tile
    const int s0   = blockIdx.x * EBLK;

    if (tid < 128) segLDS[tid] = slotseg[s0 + tid];
    if (tid == 0) segedge[0] = slotseg[s0 - 1];
    if (tid == 1) segedge[1] = slotseg[s0 + EBLK];

    {
        const int m  = (tid & 15) | (w << 4);
        const int gg = (tid >> 4) & 3;
        const int slot = s0 + m;
        const int g = elist[slot];
        int first, second;
        if (g < E) { first = ni[g];     second = bi[g];     }
        else       { first = bi[g - E]; second = ni[g - E]; }
        #pragma unroll
        for (int kt = 0; kt < 2; ++kt) {
            const int k0 = kt * 32 + gg * 8;
            const float4* pa = (const float4*)(p + (size_t)first  * DDIM + k0);
            const float4* pb = (const float4*)(p + (size_t)second * DDIM + 64 + k0);
            const float4 a0 = pa[0], a1 = pa[1], b0 = pb[0], b1 = pb[1];
            float x[8] = { a0.x + b0.x, a0.y + b0.y, a0.z + b0.z, a0.w + b0.w,
                           a1.x + b1.x, a1.y + b1.y, a1.z + b1.z, a1.w + b1.w };
            s16x8 hi8, lo8;
            #pragma unroll
            for (int j = 0; j < 8; ++j) {
                const float v = gelu_fast(x[j]);
                u16 hb = f2bf(v);
                hi8[j] = (short)hb;
                lo8[j] = (short)f2bf(v - bf2f(hb));
            }
            const int off = (kt * 8 + w) * 512 + lane * 8;
            *(s16x8*)(smA + off)        = hi8;
            *(s16x8*)(smA + 8192 + off) = lo8;
        }
    }
    // no barrier: wave w staged exactly the segments (kt*8+w) it reads.

    const int mt = w;
    for (int L = 0; L < 2; ++L) {
        f32x4 acc[4];
        #pragma unroll
        for (int nt = 0; nt < 4; ++nt) {
            const float bv = bhid[L * 64 + nt * 16 + (lane & 15)];
            acc[nt] = (f32x4){bv, bv, bv, bv};
        }
        #pragma unroll
        for (int kt = 0; kt < 2; ++kt) {
            const s16x8 aH = *(const s16x8*)(smA + (kt * 8 + mt) * 512 + lane * 8);
            const s16x8 aL = *(const s16x8*)(smA + 8192 + (kt * 8 + mt) * 512 + lane * 8);
            #pragma unroll
            for (int nt = 0; nt < 4; ++nt) {
                const int bidx = (L * 8 + kt * 4 + nt) * 64 + lane;
                const s16x8 bH = ((const s16x8*)BhH)[bidx];
                const s16x8 bL = ((const s16x8*)BhL)[bidx];
                acc[nt] = __builtin_amdgcn_mfma_f32_16x16x32_bf16(aH, bH, acc[nt], 0, 0, 0);
                acc[nt] = __builtin_amdgcn_mfma_f32_16x16x32_bf16(aH, bL, acc[nt], 0, 0, 0);
                acc[nt] = __builtin_amdgcn_mfma_f32_16x16x32_bf16(aL, bH, acc[nt], 0, 0, 0);
            }
        }
        #pragma unroll
        for (int nt = 0; nt < 4; ++nt) {
            #pragma unroll
            for (int r = 0; r < 4; ++r) {
                const float v = gelu_fast(acc[nt][r]);
                const int ml  = (lane >> 4) * 4 + r;
                const int k   = nt * 16 + (lane & 15);
                const int kt2 = k >> 5, gg = (k >> 3) & 3, j = k & 7;
                const int off = (kt2 * 8 + mt) * 512 + (ml + 16 * gg) * 8 + j;
                u16 hb = f2bf(v);
                smA[off]        = (short)hb;
                smA[8192 + off] = (short)f2bf(v - bf2f(hb));
            }
        }
    }

    float gl[4][4];
    {
        f32x4 acc[4];
        #pragma unroll
        for (int nt = 0; nt < 4; ++nt) {
            const float bv = bhid[2 * 64 + nt * 16 + (lane & 15)];
            acc[nt] = (f32x4){bv, bv, bv, bv};
        }
        #pragma unroll
        for (int kt = 0; kt < 2; ++kt) {
            const s16x8 aH = *(const s16x8*)(smA + (kt * 8 + mt) * 512 + lane * 8);
            const s16x8 aL = *(const s16x8*)(smA + 8192 + (kt * 8 + mt) * 512 + lane * 8);
            #pragma unroll
            for (int nt = 0; nt < 4; ++nt) {
                const int bidx = (2 * 8 + kt * 4 + nt) * 64 + lane;
                const s16x8 bH = ((const s16x8*)BhH)[bidx];
                const s16x8 bL = ((const s16x8*)BhL)[bidx];
                acc[nt] = __builtin_amdgcn_mfma_f32_16x16x32_bf16(aH, bH, acc[nt], 0, 0, 0);
                acc[nt] = __builtin_amdgcn_mfma_f32_16x16x32_bf16(aH, bL, acc[nt], 0, 0, 0);
                acc[nt] = __builtin_amdgcn_mfma_f32_16x16x32_bf16(aL, bH, acc[nt], 0, 0, 0);
            }
        }
        #pragma unroll
        for (int nt = 0; nt < 4; ++nt)
            #pragma unroll
            for (int r = 0; r < 4; ++r)
                gl[nt][r] = gelu_fast(acc[nt][r]);
    }

    __syncthreads();   // all frag reads done before scat overlays them
    #pragma unroll
    for (int nt = 0; nt < 4; ++nt)
        #pragma unroll
        for (int r = 0; r < 4; ++r)
            scat[(mt * 16 + (lane >> 4) * 4 + r) * 68 + nt * 16 + (lane & 15)]
                = gl[nt][r];
    __syncthreads();

    if (tid < 256) {
        const int col = tid & 63;
        const int r0  = (tid >> 6) * 32;
        const int r1  = r0 + 32;
        int   runSeg = -2;
        float runacc = 0.0f;
        bool  leftC  = true;
        for (int rowi = r0; rowi < r1; ++rowi) {
            const int sg = segLDS[rowi];
            const float v = scat[rowi * 68 + col];
            if (sg != runSeg) {
                if (runSeg >= 0) {
                    float* pp = sbuf + (size_t)runSeg * 64 + col;
                    if (leftC) *pp = runacc;
                    else       atomicAdd(pp, runacc);
                }
                runSeg = sg;
                runacc = v;
                if (rowi == r0) {
                    const int prev = (rowi == 0) ? segedge[0] : segLDS[rowi - 1];
                    leftC = (prev != sg);
                } else {
                    leftC = true;
                }
            } else {
                runacc += v;
            }
        }
        if (runSeg >= 0) {
            const int nxt = (r1 == 128) ? segedge[1] : segLDS[r1];
            const bool rightC = (nxt != runSeg);
            float* pp = sbuf + (size_t)runSeg * 64 + col;
            if (leftC && rightC) *pp = runacc;
            else                 atomicAdd(pp, runacc);
        }
    }
}

// ---------------------------------------------------------------------------
// MFMA GRU, R28/R30: composite gate-x. 64 nodes / 256 thr / 4 waves.
// wave w: jg=w&1, mh=w>>1 (m-tiles 2mh,2mh+1). Phases:
//  A: stage Smean=S*ci (K=64)   B: gate-x GEMM (z,r,xh; Bx=Wout@Wx)
//  C: stage h (K=128)           D: gate-h GEMM (z,r,hh; Bh=Wh)
//  E: epilogue (hv from LDS; bc bias gated by deg>0) -> h' in place
//  F: scatter h' -> pre frags   G: node_pre GEMM -> p
// 5 barriers, 528 MFMA/wave. (256,3): VGPR-feasible ceiling (R26 lesson).
// ---------------------------------------------------------------------------
__global__ __launch_bounds__(256, 3) void gru_mfma_kernel(
    float* __restrict__ hio, const float* __restrict__ Ssum,
    const int* __restrict__ deg,
    const u16* __restrict__ BxH, const u16* __restrict__ BxL,
    const u16* __restrict__ BhH, const u16* __restrict__ BhL,
    const float* __restrict__ bc,
    const float* __restrict__ bi_, const float* __restrict__ br_,
    const u16* __restrict__ BpH, const u16* __restrict__ BpL,
    const float* __restrict__ binp,
    float* __restrict__ pout)
{
    __shared__ short sm[16384];   // 32 KB exact: hi [0,8192), lo [8192,16384)
    const int tid  = threadIdx.x;
    const int lane = tid & 63;
    const int w    = tid >> 6;    // 0..3
    const int jg   = w & 1;
    const int mh   = w >> 1;      // m-half
    const int nbase = blockIdx.x * 64;

    const int mS = tid >> 2, q = tid & 3;   // staging row / lane-quarter
    const int nodeS = nbase + mS;
    const int laneS = (mS & 15) + 16 * q;
    const int seg_m = mS >> 4;
    const int dg = deg[nodeS];
    const float ci = (dg > 0) ? fast_rcp((float)dg) : 0.0f;

    // ---- Phase A: stage Smean fragments (K=64) ----
    #pragma unroll
    for (int c = 0; c < 2; ++c) {
        const int kl = c * 32 + q * 8;
        const float* src = Ssum + (size_t)nodeS * 64 + kl;
        const float4 v0 = ((const float4*)src)[0];
        const float4 v1 = ((const float4*)src)[1];
        float xv[8] = { v0.x * ci, v0.y * ci, v0.z * ci, v0.w * ci,
                        v1.x * ci, v1.y * ci, v1.z * ci, v1.w * ci };
        s16x8 hi8, lo8;
        #pragma unroll
        for (int i = 0; i < 8; ++i) {
            u16 hb = f2bf(xv[i]);
            hi8[i] = (short)hb;
            lo8[i] = (short)f2bf(xv[i] - bf2f(hb));
        }
        const int off = (c * 4 + seg_m) * 512 + laneS * 8;
        *(s16x8*)(sm + off)        = hi8;
        *(s16x8*)(sm + off + 8192) = lo8;
    }
    __syncthreads();

    // ---- Phase B: gate-x GEMM (z, r, xh over K=64 via composite Bx) ----
    f32x4 acc[2][4][4];
    #pragma unroll
    for (int mf = 0; mf < 2; ++mf)
        #pragma unroll
        for (int g = 0; g < 4; ++g)
            #pragma unroll
            for (int t4 = 0; t4 < 4; ++t4)
                acc[mf][g][t4] = (f32x4){0.f, 0.f, 0.f, 0.f};

    {
        const s16x8* Bx8 = (const s16x8*)BxH;
        const s16x8* Bxl8 = (const s16x8*)BxL;
        #pragma unroll
        for (int kt = 0; kt < 2; ++kt) {
            const int a0off = (kt * 4 + 2 * mh) * 512 + lane * 8;
            const s16x8 aH0 = *(const s16x8*)(sm + a0off);
            const s16x8 aL0 = *(const s16x8*)(sm + 8192 + a0off);
            const s16x8 aH1 = *(const s16x8*)(sm + a0off + 512);
            const s16x8 aL1 = *(const s16x8*)(sm + 8192 + a0off + 512);
            #pragma unroll
            for (int g = 0; g < 3; ++g) {      // z, r, xh
                #pragma unroll
                for (int t4 = 0; t4 < 4; ++t4) {
                    const int idx = (kt * 24 + g * 8 + jg * 4 + t4) * 64 + lane;
                    const s16x8 bH = Bx8[idx];
                    const s16x8 bL = Bxl8[idx];
                    acc[0][g][t4] = __builtin_amdgcn_mfma_f32_16x16x32_bf16(aH0, bH, acc[0][g][t4], 0, 0, 0);
                    acc[0][g][t4] = __builtin_amdgcn_mfma_f32_16x16x32_bf16(aH0, bL, acc[0][g][t4], 0, 0, 0);
                    acc[0][g][t4] = __builtin_amdgcn_mfma_f32_16x16x32_bf16(aL0, bH, acc[0][g][t4], 0, 0, 0);
                    acc[1][g][t4] = __builtin_amdgcn_mfma_f32_16x16x32_bf16(aH1, bH, acc[1][g][t4], 0, 0, 0);
                    acc[1][g][t4] = __builtin_amdgcn_mfma_f32_16x16x32_bf16(aH1, bL, acc[1][g][t4], 0, 0, 0);
                    acc[1][g][t4] = __builtin_amdgcn_mfma_f32_16x16x32_bf16(aL1, bH, acc[1][g][t4], 0, 0, 0);
                }
            }
        }
    }
    __syncthreads();   // Smean frag reads done; sm reused for h frags

    // ---- Phase C: stage h fragments (K=128) ----
    #pragma unroll
    for (int c = 0; c < 4; ++c) {
        const int kl = c * 32 + q * 8;
        const float* src = hio + (size_t)nodeS * DDIM + kl;
        const float4 v0 = ((const float4*)src)[0];
        const float4 v1 = ((const float4*)src)[1];
        float xv[8] = { v0.x, v0.y, v0.z, v0.w, v1.x, v1.y, v1.z, v1.w };
        s16x8 hi8, lo8;
        #pragma unroll
        for (int i = 0; i < 8; ++i) {
            u16 hb = f2bf(xv[i]);
            hi8[i] = (short)hb;
            lo8[i] = (short)f2bf(xv[i] - bf2f(hb));
        }
        const int off = (c * 4 + seg_m) * 512 + laneS * 8;
        *(s16x8*)(sm + off)        = hi8;
        *(s16x8*)(sm + off + 8192) = lo8;
    }
    __syncthreads();

    // ---- Phase D: gate-h GEMM (z, r, hh over K=128 via Bh) ----
    {
        const s16x8* Bh8 = (const s16x8*)BhH;
        const s16x8* Bhl8 = (const s16x8*)BhL;
        #pragma unroll
        for (int kt = 0; kt < 4; ++kt) {
            const int a0off = (kt * 4 + 2 * mh) * 512 + lane * 8;
            const s16x8 aH0 = *(const s16x8*)(sm + a0off);
            const s16x8 aL0 = *(const s16x8*)(sm + 8192 + a0off);
            const s16x8 aH1 = *(const s16x8*)(sm + a0off + 512);
            const s16x8 aL1 = *(const s16x8*)(sm + 8192 + a0off + 512);
            #pragma unroll
            for (int s = 0; s < 3; ++s) {
                const int g = (s == 2) ? 3 : s;   // z, r, hh
                #pragma unroll
                for (int t4 = 0; t4 < 4; ++t4) {
                    const int idx = (kt * 24 + s * 8 + jg * 4 + t4) * 64 + lane;
                    const s16x8 bH = Bh8[idx];
                    const s16x8 bL = Bhl8[idx];
                    acc[0][g][t4] = __builtin_amdgcn_mfma_f32_16x16x32_bf16(aH0, bH, acc[0][g][t4], 0, 0, 0);
                    acc[0][g][t4] = __builtin_amdgcn_mfma_f32_16x16x32_bf16(aH0, bL, acc[0][g][t4], 0, 0, 0);
                    acc[0][g][t4] = __builtin_amdgcn_mfma_f32_16x16x32_bf16(aL0, bH, acc[0][g][t4], 0, 0, 0);
                    acc[1][g][t4] = __builtin_amdgcn_mfma_f32_16x16x32_bf16(aH1, bH, acc[1][g][t4], 0, 0, 0);
                    acc[1][g][t4] = __builtin_amdgcn_mfma_f32_16x16x32_bf16(aH1, bL, acc[1][g][t4], 0, 0, 0);
                    acc[1][g][t4] = __builtin_amdgcn_mfma_f32_16x16x32_bf16(aL1, bH, acc[1][g][t4], 0, 0, 0);
                }
            }
        }
    }

    // ---- Phase E: epilogue -> h' (hv from resident LDS h frags) ----
    bool bon[2][4];
    #pragma unroll
    for (int mf = 0; mf < 2; ++mf)
        #pragma unroll
        for (int r = 0; r < 4; ++r)
            bon[mf][r] = deg[nbase + (2 * mh + mf) * 16 + (lane >> 4) * 4 + r] > 0;

    float hn[2][4][4];
    #pragma unroll
    for (int t4 = 0; t4 < 4; ++t4) {
        const int j = jg * 64 + t4 * 16 + (lane & 15);
        const float b_az = bi_[j]       + br_[j];
        const float b_ar = bi_[128 + j] + br_[128 + j];
        const float b_xh = bi_[256 + j];
        const float b_hh = br_[256 + j];
        const float bcz = bc[j];
        const float bcr = bc[128 + j];
        const float bcx = bc[256 + j];
        const int jbase = (j >> 5) * 2048 + ((j >> 3) & 3) * 128 + (j & 7);
        #pragma unroll
        for (int mf = 0; mf < 2; ++mf) {
            const int mtile = 2 * mh + mf;
            #pragma unroll
            for (int r = 0; r < 4; ++r) {
                const int m15 = (lane >> 4) * 4 + r;
                const int off = jbase + mtile * 512 + m15 * 8;
                const float hv = bf2f((u16)sm[off]) + bf2f((u16)sm[8192 + off]);
                const int m = mtile * 16 + m15;
                const float bsel = bon[mf][r] ? 1.0f : 0.0f;
                const float az = acc[mf][0][t4][r] + b_az + bsel * bcz;
                const float ar = acc[mf][1][t4][r] + b_ar + bsel * bcr;
                const float xh = acc[mf][2][t4][r] + b_xh + bsel * bcx;
                const float hh = acc[mf][3][t4][r] + b_hh;
                const float z    = sigmoid_fast(az);
                const float rr   = sigmoid_fast(ar);
                const float cand = tanh_fast(xh + rr * hh);
                const float v    = z * hv + (1.0f - z) * cand;
                hio[(size_t)(nbase + m) * DDIM + j] = v;
                hn[mf][t4][r] = v;
            }
        }
    }
    __syncthreads();   // h-frag LDS reads done; reuse sm for pre-A frags

    // ---- Phase F: scatter h' into node_pre A-frag layout ----
    #pragma unroll
    for (int mf = 0; mf < 2; ++mf) {
        const int mtile = 2 * mh + mf;
        #pragma unroll
        for (int t4 = 0; t4 < 4; ++t4) {
            #pragma unroll
            for (int r = 0; r < 4; ++r) {
                const int m15 = (lane >> 4) * 4 + r;
                const int j   = jg * 64 + t4 * 16 + (lane & 15);
                const int kt2 = j >> 5, gg = (j >> 3) & 3, jj = j & 7;
                const int off = (kt2 * 4 + mtile) * 512 + (m15 + 16 * gg) * 8 + jj;
                const float v = hn[mf][t4][r];
                u16 hb = f2bf(v);
                sm[off]        = (short)hb;
                sm[off + 8192] = (short)f2bf(v - bf2f(hb));
            }
        }
    }
    __syncthreads();

    // ---- Phase G: node_pre GEMM -> p ----
    f32x4 acc2[2][4];
    #pragma unroll
    for (int mf = 0; mf < 2; ++mf)
        #pragma unroll
        for (int t4 = 0; t4 < 4; ++t4)
            acc2[mf][t4] = (f32x4){0.f, 0.f, 0.f, 0.f};

    const s16x8* Ph8 = (const s16x8*)BpH;
    const s16x8* Pl8 = (const s16x8*)BpL;
    #pragma unroll
    for (int kt2 = 0; kt2 < 4; ++kt2) {
        const int a0off = (kt2 * 4 + 2 * mh) * 512 + lane * 8;
        const s16x8 aH0 = *(const s16x8*)(sm + a0off);
        const s16x8 aL0 = *(const s16x8*)(sm + 8192 + a0off);
        const s16x8 aH1 = *(const s16x8*)(sm + a0off + 512);
        const s16x8 aL1 = *(const s16x8*)(sm + 8192 + a0off + 512);
        #pragma unroll
        for (int t4 = 0; t4 < 4; ++t4) {
            const int idx = (kt2 * 8 + jg * 4 + t4) * 64 + lane;
            const s16x8 bH = Ph8[idx];
            const s16x8 bL = Pl8[idx];
            acc2[0][t4] = __builtin_amdgcn_mfma_f32_16x16x32_bf16(aH0, bH, acc2[0][t4], 0, 0, 0);
            acc2[0][t4] = __builtin_amdgcn_mfma_f32_16x16x32_bf16(aH0, bL, acc2[0][t4], 0, 0, 0);
            acc2[0][t4] = __builtin_amdgcn_mfma_f32_16x16x32_bf16(aL0, bH, acc2[0][t4], 0, 0, 0);
            acc2[1][t4] = __builtin_amdgcn_mfma_f32_16x16x32_bf16(aH1, bH, acc2[1][t4], 0, 0, 0);
            acc2[1][t4] = __builtin_amdgcn_mfma_f32_16x16x32_bf16(aH1, bL, acc2[1][t4], 0, 0, 0);
            acc2[1][t4] = __builtin_amdgcn_mfma_f32_16x16x32_bf16(aL1, bH, acc2[1][t4], 0, 0, 0);
        }
    }
    #pragma unroll
    for (int mf = 0; mf < 2; ++mf) {
        const int mtile = 2 * mh + mf;
        #pragma unroll
        for (int t4 = 0; t4 < 4; ++t4) {
            const int n = jg * 64 + t4 * 16 + (lane & 15);
            const float badd = (n < 64) ? binp[n] : 0.0f;
            #pragma unroll
            for (int r = 0; r < 4; ++r) {
                const int m = mtile * 16 + (lane >> 4) * 4 + r;
                pout[(size_t)(nbase + m) * DDIM + n] = acc2[mf][t4][r] + badd;
            }
        }
    }
}

// Readout: block=64, LDS activation slices, scalar weights.
__global__ __launch_bounds__(64) void readout_kernel(
    const float* __restrict__ h,
    const float* __restrict__ Win,  const float* __restrict__ bin,
    const float* __restrict__ Whid, const float* __restrict__ bhid,
    const float* __restrict__ Wout, const float* __restrict__ bout,
    float* __restrict__ out)
{
    __shared__ float xs[64 * 65];
    const int tid = threadIdx.x;
    const int row = blockIdx.x * 64 + tid;
    const int b = row / 1000, n = row % 1000;
    const float4* xrow = (const float4*)(h + ((size_t)b * 4000 + n) * DDIM);

    {
        float acc[64];
        #pragma unroll
        for (int j = 0; j < 64; ++j) acc[j] = bin[j];
        #pragma unroll 2
        for (int k4 = 0; k4 < 32; ++k4) {
            float4 xv = xrow[k4];
            #pragma unroll
            for (int kk = 0; kk < 4; ++kk) {
                const float xk = (&xv.x)[kk];
                const float* wr = Win + (size_t)(k4 * 4 + kk) * 64;
                #pragma unroll
                for (int j = 0; j < 64; ++j) acc[j] = fmaf(xk, wr[j], acc[j]);
            }
        }
        #pragma unroll
        for (int j = 0; j < 64; ++j) xs[tid * 65 + j] = gelu_fast(acc[j]);
    }

    for (int L = 0; L < 3; ++L) {
        float acc[64];
        #pragma unroll
        for (int j = 0; j < 64; ++j) acc[j] = bhid[L * 64 + j];
        #pragma unroll 4
        for (int k = 0; k < 64; ++k) {
            const float xk = xs[tid * 65 + k];
            const float* wr = Whid + (size_t)L * 4096 + (size_t)k * 64;
            #pragma unroll
            for (int j = 0; j < 64; ++j) acc[j] = fmaf(xk, wr[j], acc[j]);
        }
        #pragma unroll
        for (int j = 0; j < 64; ++j) xs[tid * 65 + j] = gelu_fast(acc[j]);
    }

    float acc[10];
    #pragma unroll
    for (int pj = 0; pj < 10; ++pj) acc[pj] = bout[pj];
    #pragma unroll 4
    for (int k = 0; k < 64; ++k) {
        const float xk = xs[tid * 65 + k];
        const float* wr = Wout + k * 10;
        #pragma unroll
        for (int pj = 0; pj < 10; ++pj) acc[pj] = fmaf(xk, wr[pj], acc[pj]);
    }
    #pragma unroll
    for (int pj = 0; pj < 10; ++pj) out[(size_t)row * 10 + pj] = acc[pj];
}

extern "C" void kernel_launch(void* const* d_in, const int* in_sizes, int n_in,
                              void* d_out, int out_size, void* d_ws, size_t ws_size,
                              hipStream_t stream) {
    const int*   node_inputs = (const int*)d_in[0];
    const int*   ni_int = (const int*)d_in[1];
    const int*   bi_int = (const int*)d_in[2];
    const int*   ni_tmp = (const int*)d_in[3];
    const int*   bi_tmp = (const int*)d_in[4];
    const float* embed  = (const float*)d_in[5];
    const float* mWin   = (const float*)d_in[6];
    const float* mbin   = (const float*)d_in[7];
    const float* mWhid  = (const float*)d_in[8];
    const float* mbhid  = (const float*)d_in[9];
    const float* mWout  = (const float*)d_in[10];
    const float* mbout  = (const float*)d_in[11];
    const float* roWin  = (const float*)d_in[12];
    const float* robin  = (const float*)d_in[13];
    const float* roWhid = (const float*)d_in[14];
    const float* robhid = (const float*)d_in[15];
    const float* roWout = (const float*)d_in[16];
    const float* robout = (const float*)d_in[17];
    const float* giWx = (const float*)d_in[18];
    const float* giWh = (const float*)d_in[19];
    const float* gibi = (const float*)d_in[20];
    const float* gibr = (const float*)d_in[21];
    const float* gtWx = (const float*)d_in[22];
    const float* gtWh = (const float*)d_in[23];
    const float* gtbi = (const float*)d_in[24];
    const float* gtbr = (const float*)d_in[25];
    float* out = (float*)d_out;

    const int E_INT = 200000, E_TMP = 96000;
    const int NSLOT_I = 400000;   // 3125*128 exact
    const int NSLOT_T = 192000;   // 1500*128 exact
    const int NBLK_I = NSLOT_I / EBLK;
    const int NBLK_T = NSLOT_T / EBLK;
    const int NS32_I = NSLOT_I / 32;   // 12500
    const int NS32_T = NSLOT_T / 32;   // 6000

    char* ws = (char*)d_ws;
    float* B0 = (float*)(ws);                 // h (in-place)
    float* B1 = (float*)(ws + HBYTES);        // p
    float* B2 = (float*)(ws + 2 * HBYTES);    // S (64-wide)
    char*  ib = ws + 3 * HBYTES;

    int* deg_i   = (int*)(ib);
    int* deg_t   = (int*)(ib + 512000);
    int* offp_i  = (int*)(ib + 1024000);
    int* offp_t  = (int*)(ib + 1536000);
    int* bexc_i  = (int*)(ib + 2048000);
    int* bexc_t  = (int*)(ib + 2052096);
    int* bsum    = (int*)(ib + 2056192);
    int* cursor  = (int*)(ib + 2060288);
    int* el_i    = (int*)(ib + 2572288);
    int* el_t    = (int*)(ib + 4172288);
    int* ssi_raw = (int*)(ib + 4940288);
    int* sst_raw = (int*)(ib + 6540296);
    // packed-weight buffers (R28 layout)
    char* fb = ib + 8114176;
    u16* BxiH = (u16*)(fb);               // 49152 B
    u16* BxiL = (u16*)(fb +  49152);
    u16* BhiH = (u16*)(fb +  98304);      // 98304 B
    u16* BhiL = (u16*)(fb + 196608);
    u16* BxtH = (u16*)(fb + 294912);
    u16* BxtL = (u16*)(fb + 344064);
    u16* BhtH = (u16*)(fb + 393216);
    u16* BhtL = (u16*)(fb + 491520);
    float* bci = (float*)(fb + 589824);   // 1536 B
    float* bct = (float*)(fb + 591360);
    u16* BpH  = (u16*)(fb + 592896);      // 32768 B
    u16* BpL  = (u16*)(fb + 625664);
    u16* EhH  = (u16*)(fb + 658432);      // 24576 B
    u16* EhL  = (u16*)(fb + 683008);
    int* str_i  = (int*)(fb + 707584);    // up to 12500 ints
    int* str_t  = (int*)(fb + 757584);    // up to 6000 ints
    int* strc_i = (int*)(fb + 781584);
    int* strc_t = (int*)(fb + 781588);
    int* ssi = ssi_raw + 1;
    int* sst = sst_raw + 1;

    embed_kernel<<<16000, 256, 0, stream>>>(node_inputs, embed, B0);

    hipMemsetAsync(deg_i, 0, NTOT * sizeof(int), stream);
    hipMemsetAsync(deg_t, 0, NTOT * sizeof(int), stream);
    hist_kernel<<<(2 * E_INT + 255) / 256, 256, 0, stream>>>(ni_int, bi_int, E_INT, deg_i);
    hist_kernel<<<(2 * E_TMP + 255) / 256, 256, 0, stream>>>(ni_tmp, bi_tmp, E_TMP, deg_t);

    hipMemsetAsync(ssi_raw, 0xFF, (size_t)(NSLOT_I + 2) * sizeof(int), stream);
    hipMemsetAsync(sst_raw, 0xFF, (size_t)(NSLOT_T + 2) * sizeof(int), stream);

    blockscan_kernel<<<500, 256, 0, stream>>>(deg_i, offp_i, bsum);
    bscan_kernel<<<1, 512, 0, stream>>>(bsum, bexc_i, 500);
    hipMemsetAsync(cursor, 0, NTOT * sizeof(int), stream);
    fill_kernel<<<(2 * E_INT + 255) / 256, 256, 0, stream>>>(
        ni_int, bi_int, E_INT, offp_i, bexc_i, cursor, el_i, ssi);

    blockscan_kernel<<<500, 256, 0, stream>>>(deg_t, offp_t, bsum);
    bscan_kernel<<<1, 512, 0, stream>>>(bsum, bexc_t, 500);
    hipMemsetAsync(cursor, 0, NTOT * sizeof(int), stream);
    fill_kernel<<<(2 * E_TMP + 255) / 256, 256, 0, stream>>>(
        ni_tmp, bi_tmp, E_TMP, offp_t, bexc_t, cursor, el_t, sst);

    hipMemsetAsync(strc_i, 0, sizeof(int), stream);
    hipMemsetAsync(strc_t, 0, sizeof(int), stream);
    straddle_kernel<<<(NS32_I + 255) / 256, 256, 0, stream>>>(ssi, NS32_I, str_i, strc_i);
    straddle_kernel<<<(NS32_T + 255) / 256, 256, 0, stream>>>(sst, NS32_T, str_t, strc_t);

    pack_gateBx_kernel<<<96, 256, 0, stream>>>(mWout, giWx, BxiH, BxiL);
    pack_gateBx_kernel<<<96, 256, 0, stream>>>(mWout, gtWx, BxtH, BxtL);
    pack_gateBh_kernel<<<192, 256, 0, stream>>>(giWh, BhiH, BhiL);
    pack_gateBh_kernel<<<192, 256, 0, stream>>>(gtWh, BhtH, BhtL);
    pack_gbias_kernel<<<2, 256, 0, stream>>>(mbout, giWx, bci);
    pack_gbias_kernel<<<2, 256, 0, stream>>>(mbout, gtWx, bct);
    pack_preB_kernel<<<64, 256, 0, stream>>>(mWin, BpH, BpL);
    pack_hidB_kernel<<<48, 256, 0, stream>>>(mWhid, EhH, EhL);

    node_pre_mfma<<<NTOT / 128, 512, 0, stream>>>(B0, BpH, BpL, mbin, B1);

    // fixed roles: h=B0 (in place), p=B1, S=B2
    for (int ph = 0; ph < 4; ++ph) {
        const bool isInt = (ph % 2 == 0);
        if (isInt) {
            zero_rows_kernel<<<NS32_I, 64, 0, stream>>>(str_i, strc_i, B2);
            edge_mlp_mfma<<<NBLK_I, 512, 0, stream>>>(
                ni_int, bi_int, E_INT, el_i, ssi, B1,
                EhH, EhL, mbhid, B2);
            gru_mfma_kernel<<<NTOT / 64, 256, 0, stream>>>(
                B0, B2, deg_i, BxiH, BxiL, BhiH, BhiL, bci,
                gibi, gibr, BpH, BpL, mbin, B1);
        } else {
            zero_rows_kernel<<<NS32_T, 64, 0, stream>>>(str_t, strc_t, B2);
            edge_mlp_mfma<<<NBLK_T, 512, 0, stream>>>(
                ni_tmp, bi_tmp, E_TMP, el_t, sst, B1,
                EhH, EhL, mbhid, B2);
            gru_mfma_kernel<<<NTOT / 64, 256, 0, stream>>>(
                B0, B2, deg_t, BxtH, BxtL, BhtH, BhtL, bct,
                gtbi, gtbr, BpH, BpL, mbin, B1);
        }
    }

    readout_kernel<<<500, 64, 0, stream>>>(
        B0, roWin, robin, roWhid, robhid, roWout, robout, out);
}